// Round 1
// baseline (510.234 us; speedup 1.0000x reference)
//
#include <hip/hip_runtime.h>
#include <math.h>

#define BB 16
#define TT 24
#define NN 128
#define DD 64
#define KH 8
#define DH 8
#define PTOT (BB * TT * NN)   // 49152 positions
#define P64  (PTOT * 64)      // elements per (B,T,N,64) buffer

// ---------------------------------------------------------------------------
// Kernel 1: fused 6-way QKV projection.  XE = [X | TLE] (192 ch) -> 6x relu(XE@W+b)
// One block = 4 positions, 64 threads (thread = output channel).
// ---------------------------------------------------------------------------
__global__ __launch_bounds__(64) void proj_kernel(
    const float* __restrict__ X, const float* __restrict__ TLE,
    const float* __restrict__ W0, const float* __restrict__ b0,
    const float* __restrict__ W1, const float* __restrict__ b1,
    const float* __restrict__ W2, const float* __restrict__ b2,
    const float* __restrict__ W3, const float* __restrict__ b3,
    const float* __restrict__ W4, const float* __restrict__ b4,
    const float* __restrict__ W5, const float* __restrict__ b5,
    float* __restrict__ o0, float* __restrict__ o1, float* __restrict__ o2,
    float* __restrict__ o3, float* __restrict__ o4, float* __restrict__ o5)
{
    constexpr int G = 4;
    __shared__ float xe[G][192];
    const int tid = threadIdx.x;
    const long p0 = (long)blockIdx.x * G;

    #pragma unroll
    for (int g = 0; g < G; ++g) {
        const long p = p0 + g;
        xe[g][tid]       = X[p * 64 + tid];
        xe[g][64 + tid]  = TLE[p * 128 + tid];
        xe[g][128 + tid] = TLE[p * 128 + 64 + tid];
    }
    __syncthreads();

    const float* Ws[6] = {W0, W1, W2, W3, W4, W5};
    const float* bs[6] = {b0, b1, b2, b3, b4, b5};
    float acc[6][G];
    #pragma unroll
    for (int j = 0; j < 6; ++j)
        #pragma unroll
        for (int g = 0; g < G; ++g)
            acc[j][g] = bs[j][tid];

    for (int k = 0; k < 192; ++k) {
        float w[6];
        #pragma unroll
        for (int j = 0; j < 6; ++j) w[j] = Ws[j][k * 64 + tid];
        #pragma unroll
        for (int g = 0; g < G; ++g) {
            const float x = xe[g][k];
            #pragma unroll
            for (int j = 0; j < 6; ++j) acc[j][g] = fmaf(x, w[j], acc[j][g]);
        }
    }

    float* Os[6] = {o0, o1, o2, o3, o4, o5};
    #pragma unroll
    for (int j = 0; j < 6; ++j)
        #pragma unroll
        for (int g = 0; g < G; ++g)
            Os[j][(p0 + g) * 64 + tid] = fmaxf(acc[j][g], 0.0f);
}

// ---------------------------------------------------------------------------
// Kernel 2: spatial attention.  One block per (b*t, head), 128 threads = query n.
// Two-pass softmax (max pass, then exp/accumulate pass recomputing dots).
// O may alias Q (each thread writes only the address it itself read).
// ---------------------------------------------------------------------------
__global__ __launch_bounds__(128) void sattn_kernel(
    const float* __restrict__ Q, const float* __restrict__ Kb,
    const float* __restrict__ V, float* __restrict__ O)
{
    __shared__ float kk[NN][DH];
    __shared__ float vv[NN][DH];
    const int n  = threadIdx.x;
    const int h  = blockIdx.x & 7;
    const int bt = blockIdx.x >> 3;
    const long my = ((long)bt * NN + n) * 64 + h * 8;

    float q[8];
    #pragma unroll
    for (int d = 0; d < 8; ++d) q[d] = Q[my + d];
    #pragma unroll
    for (int d = 0; d < 8; ++d) { kk[n][d] = Kb[my + d]; vv[n][d] = V[my + d]; }
    __syncthreads();

    const float scale = 0.35355339059327373f;  // 1/sqrt(8)

    float mx = -1e30f;
    for (int m = 0; m < NN; ++m) {
        float s = 0.0f;
        #pragma unroll
        for (int d = 0; d < 8; ++d) s = fmaf(q[d], kk[m][d], s);
        mx = fmaxf(mx, s * scale);
    }

    float sum = 0.0f;
    float acc[8];
    #pragma unroll
    for (int d = 0; d < 8; ++d) acc[d] = 0.0f;
    for (int m = 0; m < NN; ++m) {
        float s = 0.0f;
        #pragma unroll
        for (int d = 0; d < 8; ++d) s = fmaf(q[d], kk[m][d], s);
        const float e = __expf(s * scale - mx);
        sum += e;
        #pragma unroll
        for (int d = 0; d < 8; ++d) acc[d] = fmaf(e, vv[m][d], acc[d]);
    }
    const float inv = 1.0f / sum;
    #pragma unroll
    for (int d = 0; d < 8; ++d) O[my + d] = acc[d] * inv;
}

// ---------------------------------------------------------------------------
// Kernel 3: temporal attention (causal + key padding).
// One block per (b, n); 192 threads = (head h, query time i).
// ---------------------------------------------------------------------------
__global__ __launch_bounds__(192) void tattn_kernel(
    const float* __restrict__ Q, const float* __restrict__ Kb,
    const float* __restrict__ V, const int* __restrict__ kpm,
    float* __restrict__ O)
{
    __shared__ float kk[KH][TT][DH];
    __shared__ float vv[KH][TT][DH];
    const int tid = threadIdx.x;
    const int n = blockIdx.x & (NN - 1);
    const int b = blockIdx.x >> 7;

    for (int f = tid; f < KH * TT * DH; f += 192) {
        const int h = f / (TT * DH);
        const int r = f % (TT * DH);
        const int j = r / DH;
        const int d = r % DH;
        const long g = (((long)(b * TT + j)) * NN + n) * 64 + h * 8 + d;
        kk[h][j][d] = Kb[g];
        vv[h][j][d] = V[g];
    }

    const int h = tid / TT;
    const int i = tid % TT;
    const long qb = (((long)(b * TT + i)) * NN + n) * 64 + h * 8;
    float q[8];
    #pragma unroll
    for (int d = 0; d < 8; ++d) q[d] = Q[qb + d];
    __syncthreads();

    const int kp = kpm[b];
    const float scale = 0.35355339059327373f;

    float s[TT];
    #pragma unroll
    for (int j = 0; j < TT; ++j) {
        float t = 0.0f;
        #pragma unroll
        for (int d = 0; d < 8; ++d) t = fmaf(q[d], kk[h][j][d], t);
        s[j] = (j <= i && j < kp) ? t * scale : -INFINITY;
    }
    float mx = -INFINITY;
    #pragma unroll
    for (int j = 0; j < TT; ++j) mx = fmaxf(mx, s[j]);

    float sum = 0.0f;
    float acc[8];
    #pragma unroll
    for (int d = 0; d < 8; ++d) acc[d] = 0.0f;
    #pragma unroll
    for (int j = 0; j < TT; ++j) {
        const float e = __expf(s[j] - mx);  // masked -> exp(-inf)=0
        sum += e;
        #pragma unroll
        for (int d = 0; d < 8; ++d) acc[d] = fmaf(e, vv[h][j][d], acc[d]);
    }
    const float inv = 1.0f / sum;
    #pragma unroll
    for (int d = 0; d < 8; ++d) O[qb + d] = acc[d] * inv;
}

// ---------------------------------------------------------------------------
// Kernel 4: epilogue — 2x (dense-relu-dense) on HS/HT, gated fusion, 2 dense, residual.
// One block per position, 64 threads = channel.
// ---------------------------------------------------------------------------
__global__ __launch_bounds__(64) void epi_kernel(
    const float* __restrict__ X,
    const float* __restrict__ HSa, const float* __restrict__ HTa,
    const float* __restrict__ sWo1, const float* __restrict__ sbo1,
    const float* __restrict__ sWo2, const float* __restrict__ sbo2,
    const float* __restrict__ tWo1, const float* __restrict__ tbo1,
    const float* __restrict__ tWo2, const float* __restrict__ tbo2,
    const float* __restrict__ Wxs, const float* __restrict__ Wxt,
    const float* __restrict__ bxt,
    const float* __restrict__ Wh1, const float* __restrict__ bh1,
    const float* __restrict__ Wh2, const float* __restrict__ bh2,
    float* __restrict__ out)
{
    __shared__ float sA[64], sB[64], sHS[64], sHT[64];
    const int c = threadIdx.x;
    const long base = (long)blockIdx.x * 64;

    // ---- HS = (relu(HSa@Wo1+bo1))@Wo2+bo2 ----
    sA[c] = HSa[base + c];
    __syncthreads();
    float t = sbo1[c];
    for (int k = 0; k < 64; ++k) t = fmaf(sA[k], sWo1[k * 64 + c], t);
    t = fmaxf(t, 0.0f);
    sB[c] = t;
    __syncthreads();
    float hs = sbo2[c];
    for (int k = 0; k < 64; ++k) hs = fmaf(sB[k], sWo2[k * 64 + c], hs);
    sHS[c] = hs;

    // ---- HT path ----
    sA[c] = HTa[base + c];          // safe: all sA reads done before last barrier
    __syncthreads();
    t = tbo1[c];
    for (int k = 0; k < 64; ++k) t = fmaf(sA[k], tWo1[k * 64 + c], t);
    t = fmaxf(t, 0.0f);
    sB[c] = t;
    __syncthreads();
    float ht = tbo2[c];
    for (int k = 0; k < 64; ++k) ht = fmaf(sB[k], tWo2[k * 64 + c], ht);
    sHT[c] = ht;
    __syncthreads();                // sHS/sHT now visible to all

    // ---- gate ----
    float za = bxt[c];
    for (int k = 0; k < 64; ++k) {
        za = fmaf(sHS[k], Wxs[k * 64 + c], za);
        za = fmaf(sHT[k], Wxt[k * 64 + c], za);
    }
    const float z = 1.0f / (1.0f + __expf(-za));
    const float hval = z * hs + (1.0f - z) * ht;

    // ---- H = (relu(H@Wh1+bh1))@Wh2+bh2 ; out = X + H ----
    __syncthreads();                // ensure everyone is done reading sHS/sHT (sA rewrite next is a different array, but keep ordering cheap & safe)
    sA[c] = hval;
    __syncthreads();
    t = bh1[c];
    for (int k = 0; k < 64; ++k) t = fmaf(sA[k], Wh1[k * 64 + c], t);
    t = fmaxf(t, 0.0f);
    sB[c] = t;
    __syncthreads();
    float o = bh2[c];
    for (int k = 0; k < 64; ++k) o = fmaf(sB[k], Wh2[k * 64 + c], o);
    out[base + c] = X[base + c] + o;
}

// ---------------------------------------------------------------------------
extern "C" void kernel_launch(void* const* d_in, const int* in_sizes, int n_in,
                              void* d_out, int out_size, void* d_ws, size_t ws_size,
                              hipStream_t stream) {
    const float* X   = (const float*)d_in[0];
    const float* TLE = (const float*)d_in[1];
    const int* kpm   = (const int*)d_in[2];

    const float* sa_Wq = (const float*)d_in[3];  const float* sa_bq = (const float*)d_in[4];
    const float* sa_Wk = (const float*)d_in[5];  const float* sa_bk = (const float*)d_in[6];
    const float* sa_Wv = (const float*)d_in[7];  const float* sa_bv = (const float*)d_in[8];
    const float* sa_Wo1 = (const float*)d_in[9];  const float* sa_bo1 = (const float*)d_in[10];
    const float* sa_Wo2 = (const float*)d_in[11]; const float* sa_bo2 = (const float*)d_in[12];
    const float* ta_Wq = (const float*)d_in[13]; const float* ta_bq = (const float*)d_in[14];
    const float* ta_Wk = (const float*)d_in[15]; const float* ta_bk = (const float*)d_in[16];
    const float* ta_Wv = (const float*)d_in[17]; const float* ta_bv = (const float*)d_in[18];
    const float* ta_Wo1 = (const float*)d_in[19]; const float* ta_bo1 = (const float*)d_in[20];
    const float* ta_Wo2 = (const float*)d_in[21]; const float* ta_bo2 = (const float*)d_in[22];
    const float* g_Wxs = (const float*)d_in[23];
    const float* g_Wxt = (const float*)d_in[24]; const float* g_bxt = (const float*)d_in[25];
    const float* g_Wh1 = (const float*)d_in[26]; const float* g_bh1 = (const float*)d_in[27];
    const float* g_Wh2 = (const float*)d_in[28]; const float* g_bh2 = (const float*)d_in[29];

    float* ws = (float*)d_ws;
    float* qs = ws + 0L * P64;
    float* ks = ws + 1L * P64;
    float* vs = ws + 2L * P64;
    float* qt = ws + 3L * P64;
    float* kt = ws + 4L * P64;
    float* vt = ws + 5L * P64;
    // attention outputs alias the q buffers (safe: see kernel comments)
    float* HS = qs;
    float* HT = qt;

    float* out = (float*)d_out;

    hipLaunchKernelGGL(proj_kernel, dim3(PTOT / 4), dim3(64), 0, stream,
                       X, TLE,
                       sa_Wq, sa_bq, sa_Wk, sa_bk, sa_Wv, sa_bv,
                       ta_Wq, ta_bq, ta_Wk, ta_bk, ta_Wv, ta_bv,
                       qs, ks, vs, qt, kt, vt);

    hipLaunchKernelGGL(sattn_kernel, dim3(BB * TT * KH), dim3(128), 0, stream,
                       qs, ks, vs, HS);

    hipLaunchKernelGGL(tattn_kernel, dim3(BB * NN), dim3(192), 0, stream,
                       qt, kt, vt, kpm, HT);

    hipLaunchKernelGGL(epi_kernel, dim3(PTOT), dim3(64), 0, stream,
                       X, HS, HT,
                       sa_Wo1, sa_bo1, sa_Wo2, sa_bo2,
                       ta_Wo1, ta_bo1, ta_Wo2, ta_bo2,
                       g_Wxs, g_Wxt, g_bxt,
                       g_Wh1, g_bh1, g_Wh2, g_bh2,
                       out);
}

// Round 3
// 420.448 us; speedup vs baseline: 1.2135x; 1.2135x over previous
//
#include <hip/hip_runtime.h>
#include <math.h>

#define BB 16
#define TT 24
#define NN 128
#define DD 64
#define KH 8
#define DH 8
#define PTOT (BB * TT * NN)   // 49152 positions
#define P64  (PTOT * 64)      // elements per (B,T,N,64) buffer

// ---------------------------------------------------------------------------
// Kernel 1: fused 6-way QKV projection.  XE = [X | TLE] (192 ch) -> 6x relu(XE@W+b)
// One block = 8 positions, 64 threads (thread = output channel).
// Per k-iter: 6 weight loads feed 48 fmas (amortization + ILP).
// ---------------------------------------------------------------------------
__global__ __launch_bounds__(64) void proj_kernel(
    const float* __restrict__ X, const float* __restrict__ TLE,
    const float* __restrict__ W0, const float* __restrict__ b0,
    const float* __restrict__ W1, const float* __restrict__ b1,
    const float* __restrict__ W2, const float* __restrict__ b2,
    const float* __restrict__ W3, const float* __restrict__ b3,
    const float* __restrict__ W4, const float* __restrict__ b4,
    const float* __restrict__ W5, const float* __restrict__ b5,
    float* __restrict__ o0, float* __restrict__ o1, float* __restrict__ o2,
    float* __restrict__ o3, float* __restrict__ o4, float* __restrict__ o5)
{
    constexpr int G = 8;
    __shared__ float xe[G][192];
    const int tid = threadIdx.x;
    const long p0 = (long)blockIdx.x * G;

    #pragma unroll
    for (int g = 0; g < G; ++g) {
        const long p = p0 + g;
        xe[g][tid]       = X[p * 64 + tid];
        xe[g][64 + tid]  = TLE[p * 128 + tid];
        xe[g][128 + tid] = TLE[p * 128 + 64 + tid];
    }
    __syncthreads();

    const float* Ws[6] = {W0, W1, W2, W3, W4, W5};
    const float* bs[6] = {b0, b1, b2, b3, b4, b5};
    float acc[6][G];
    #pragma unroll
    for (int j = 0; j < 6; ++j)
        #pragma unroll
        for (int g = 0; g < G; ++g)
            acc[j][g] = bs[j][tid];

    for (int k = 0; k < 192; ++k) {
        float w[6];
        #pragma unroll
        for (int j = 0; j < 6; ++j) w[j] = Ws[j][k * 64 + tid];
        #pragma unroll
        for (int g = 0; g < G; ++g) {
            const float x = xe[g][k];
            #pragma unroll
            for (int j = 0; j < 6; ++j) acc[j][g] = fmaf(x, w[j], acc[j][g]);
        }
    }

    float* Os[6] = {o0, o1, o2, o3, o4, o5};
    #pragma unroll
    for (int j = 0; j < 6; ++j)
        #pragma unroll
        for (int g = 0; g < G; ++g)
            Os[j][(p0 + g) * 64 + tid] = fmaxf(acc[j][g], 0.0f);
}

// ---------------------------------------------------------------------------
// Kernel 2: spatial attention.  One block per (b*t, head), 128 threads = query n.
// Two-pass softmax (max pass, then exp/accumulate pass recomputing dots).
// O may alias Q (each thread writes only the address it itself read).
// ---------------------------------------------------------------------------
__global__ __launch_bounds__(128) void sattn_kernel(
    const float* __restrict__ Q, const float* __restrict__ Kb,
    const float* __restrict__ V, float* __restrict__ O)
{
    __shared__ float kk[NN][DH];
    __shared__ float vv[NN][DH];
    const int n  = threadIdx.x;
    const int h  = blockIdx.x & 7;
    const int bt = blockIdx.x >> 3;
    const long my = ((long)bt * NN + n) * 64 + h * 8;

    float q[8];
    #pragma unroll
    for (int d = 0; d < 8; ++d) q[d] = Q[my + d];
    #pragma unroll
    for (int d = 0; d < 8; ++d) { kk[n][d] = Kb[my + d]; vv[n][d] = V[my + d]; }
    __syncthreads();

    const float scale = 0.35355339059327373f;  // 1/sqrt(8)

    float mx = -1e30f;
    for (int m = 0; m < NN; ++m) {
        float s = 0.0f;
        #pragma unroll
        for (int d = 0; d < 8; ++d) s = fmaf(q[d], kk[m][d], s);
        mx = fmaxf(mx, s * scale);
    }

    float sum = 0.0f;
    float acc[8];
    #pragma unroll
    for (int d = 0; d < 8; ++d) acc[d] = 0.0f;
    for (int m = 0; m < NN; ++m) {
        float s = 0.0f;
        #pragma unroll
        for (int d = 0; d < 8; ++d) s = fmaf(q[d], kk[m][d], s);
        const float e = __expf(s * scale - mx);
        sum += e;
        #pragma unroll
        for (int d = 0; d < 8; ++d) acc[d] = fmaf(e, vv[m][d], acc[d]);
    }
    const float inv = 1.0f / sum;
    #pragma unroll
    for (int d = 0; d < 8; ++d) O[my + d] = acc[d] * inv;
}

// ---------------------------------------------------------------------------
// Kernel 3: temporal attention (causal + key padding).
// One block per (b, n); 192 threads = (head h, query time i).
// ---------------------------------------------------------------------------
__global__ __launch_bounds__(192) void tattn_kernel(
    const float* __restrict__ Q, const float* __restrict__ Kb,
    const float* __restrict__ V, const int* __restrict__ kpm,
    float* __restrict__ O)
{
    __shared__ float kk[KH][TT][DH];
    __shared__ float vv[KH][TT][DH];
    const int tid = threadIdx.x;
    const int n = blockIdx.x & (NN - 1);
    const int b = blockIdx.x >> 7;

    for (int f = tid; f < KH * TT * DH; f += 192) {
        const int h = f / (TT * DH);
        const int r = f % (TT * DH);
        const int j = r / DH;
        const int d = r % DH;
        const long g = (((long)(b * TT + j)) * NN + n) * 64 + h * 8 + d;
        kk[h][j][d] = Kb[g];
        vv[h][j][d] = V[g];
    }

    const int h = tid / TT;
    const int i = tid % TT;
    const long qb = (((long)(b * TT + i)) * NN + n) * 64 + h * 8;
    float q[8];
    #pragma unroll
    for (int d = 0; d < 8; ++d) q[d] = Q[qb + d];
    __syncthreads();

    const int kp = kpm[b];
    const float scale = 0.35355339059327373f;

    float s[TT];
    #pragma unroll
    for (int j = 0; j < TT; ++j) {
        float t = 0.0f;
        #pragma unroll
        for (int d = 0; d < 8; ++d) t = fmaf(q[d], kk[h][j][d], t);
        s[j] = (j <= i && j < kp) ? t * scale : -INFINITY;
    }
    float mx = -INFINITY;
    #pragma unroll
    for (int j = 0; j < TT; ++j) mx = fmaxf(mx, s[j]);

    float sum = 0.0f;
    float acc[8];
    #pragma unroll
    for (int d = 0; d < 8; ++d) acc[d] = 0.0f;
    #pragma unroll
    for (int j = 0; j < TT; ++j) {
        const float e = __expf(s[j] - mx);  // masked -> exp(-inf)=0
        sum += e;
        #pragma unroll
        for (int d = 0; d < 8; ++d) acc[d] = fmaf(e, vv[h][j][d], acc[d]);
    }
    const float inv = 1.0f / sum;
    #pragma unroll
    for (int d = 0; d < 8; ++d) O[qb + d] = acc[d] * inv;
}

// ---------------------------------------------------------------------------
// Kernel 4: epilogue — 2x (dense-relu-dense), gated fusion, dense-relu-dense,
// residual.  One block = 8 positions, 64 threads (thread = channel).
// Each weight load feeds 8 fmas (G-way ILP breaks the serial fma chain).
// GRID MUST BE PTOT/8.
// ---------------------------------------------------------------------------
__global__ __launch_bounds__(64) void epi_kernel(
    const float* __restrict__ X,
    const float* __restrict__ HSa, const float* __restrict__ HTa,
    const float* __restrict__ sWo1, const float* __restrict__ sbo1,
    const float* __restrict__ sWo2, const float* __restrict__ sbo2,
    const float* __restrict__ tWo1, const float* __restrict__ tbo1,
    const float* __restrict__ tWo2, const float* __restrict__ tbo2,
    const float* __restrict__ Wxs, const float* __restrict__ Wxt,
    const float* __restrict__ bxt,
    const float* __restrict__ Wh1, const float* __restrict__ bh1,
    const float* __restrict__ Wh2, const float* __restrict__ bh2,
    float* __restrict__ out)
{
    constexpr int G = 8;
    __shared__ float sA[G][64], sB[G][64], sHS[G][64], sHT[G][64];
    const int c = threadIdx.x;
    const long base = (long)blockIdx.x * G * 64;

    float acc[G];

    // ---- load HSa tile ----
    #pragma unroll
    for (int g = 0; g < G; ++g) sA[g][c] = HSa[base + g * 64 + c];
    __syncthreads();

    // ---- stage 1: sB = relu(sA @ sWo1 + sbo1) ----
    #pragma unroll
    for (int g = 0; g < G; ++g) acc[g] = sbo1[c];
    for (int k = 0; k < 64; ++k) {
        const float w = sWo1[k * 64 + c];
        #pragma unroll
        for (int g = 0; g < G; ++g) acc[g] = fmaf(sA[g][k], w, acc[g]);
    }
    #pragma unroll
    for (int g = 0; g < G; ++g) sB[g][c] = fmaxf(acc[g], 0.0f);
    __syncthreads();   // stage-1 reads of sA done; sB visible

    // ---- stage 2: hs = sB @ sWo2 + sbo2 ; also refill sA with HTa ----
    #pragma unroll
    for (int g = 0; g < G; ++g) acc[g] = sbo2[c];
    for (int k = 0; k < 64; ++k) {
        const float w = sWo2[k * 64 + c];
        #pragma unroll
        for (int g = 0; g < G; ++g) acc[g] = fmaf(sB[g][k], w, acc[g]);
    }
    float hs[G];
    #pragma unroll
    for (int g = 0; g < G; ++g) { hs[g] = acc[g]; sHS[g][c] = acc[g]; }
    #pragma unroll
    for (int g = 0; g < G; ++g) sA[g][c] = HTa[base + g * 64 + c];
    __syncthreads();   // sA(HTa) + sHS visible; stage-2 reads of sB done

    // ---- stage 3: sB = relu(sA @ tWo1 + tbo1) ----
    #pragma unroll
    for (int g = 0; g < G; ++g) acc[g] = tbo1[c];
    for (int k = 0; k < 64; ++k) {
        const float w = tWo1[k * 64 + c];
        #pragma unroll
        for (int g = 0; g < G; ++g) acc[g] = fmaf(sA[g][k], w, acc[g]);
    }
    #pragma unroll
    for (int g = 0; g < G; ++g) sB[g][c] = fmaxf(acc[g], 0.0f);
    __syncthreads();

    // ---- stage 4: ht = sB @ tWo2 + tbo2 ----
    #pragma unroll
    for (int g = 0; g < G; ++g) acc[g] = tbo2[c];
    for (int k = 0; k < 64; ++k) {
        const float w = tWo2[k * 64 + c];
        #pragma unroll
        for (int g = 0; g < G; ++g) acc[g] = fmaf(sB[g][k], w, acc[g]);
    }
    float ht[G];
    #pragma unroll
    for (int g = 0; g < G; ++g) { ht[g] = acc[g]; sHT[g][c] = acc[g]; }
    __syncthreads();   // sHT visible; stage-3/4 reads of sA/sB done

    // ---- gate: z = sigmoid(HS@Wxs + HT@Wxt + bxt); hval = z*hs+(1-z)*ht ----
    #pragma unroll
    for (int g = 0; g < G; ++g) acc[g] = bxt[c];
    for (int k = 0; k < 64; ++k) {
        const float ws = Wxs[k * 64 + c];
        const float wt = Wxt[k * 64 + c];
        #pragma unroll
        for (int g = 0; g < G; ++g) {
            acc[g] = fmaf(sHS[g][k], ws, acc[g]);
            acc[g] = fmaf(sHT[g][k], wt, acc[g]);
        }
    }
    __syncthreads();   // all gate reads of sHS/sHT done before sA overwrite
    #pragma unroll
    for (int g = 0; g < G; ++g) {
        const float z = 1.0f / (1.0f + __expf(-acc[g]));
        sA[g][c] = z * hs[g] + (1.0f - z) * ht[g];
    }
    __syncthreads();

    // ---- stage 5: sB = relu(sA @ Wh1 + bh1) ----
    #pragma unroll
    for (int g = 0; g < G; ++g) acc[g] = bh1[c];
    for (int k = 0; k < 64; ++k) {
        const float w = Wh1[k * 64 + c];
        #pragma unroll
        for (int g = 0; g < G; ++g) acc[g] = fmaf(sA[g][k], w, acc[g]);
    }
    #pragma unroll
    for (int g = 0; g < G; ++g) sB[g][c] = fmaxf(acc[g], 0.0f);
    __syncthreads();

    // ---- stage 6: out = X + sB @ Wh2 + bh2 ----
    #pragma unroll
    for (int g = 0; g < G; ++g) acc[g] = bh2[c];
    for (int k = 0; k < 64; ++k) {
        const float w = Wh2[k * 64 + c];
        #pragma unroll
        for (int g = 0; g < G; ++g) acc[g] = fmaf(sB[g][k], w, acc[g]);
    }
    #pragma unroll
    for (int g = 0; g < G; ++g)
        out[base + g * 64 + c] = X[base + g * 64 + c] + acc[g];
}

// ---------------------------------------------------------------------------
extern "C" void kernel_launch(void* const* d_in, const int* in_sizes, int n_in,
                              void* d_out, int out_size, void* d_ws, size_t ws_size,
                              hipStream_t stream) {
    const float* X   = (const float*)d_in[0];
    const float* TLE = (const float*)d_in[1];
    const int* kpm   = (const int*)d_in[2];

    const float* sa_Wq = (const float*)d_in[3];  const float* sa_bq = (const float*)d_in[4];
    const float* sa_Wk = (const float*)d_in[5];  const float* sa_bk = (const float*)d_in[6];
    const float* sa_Wv = (const float*)d_in[7];  const float* sa_bv = (const float*)d_in[8];
    const float* sa_Wo1 = (const float*)d_in[9];  const float* sa_bo1 = (const float*)d_in[10];
    const float* sa_Wo2 = (const float*)d_in[11]; const float* sa_bo2 = (const float*)d_in[12];
    const float* ta_Wq = (const float*)d_in[13]; const float* ta_bq = (const float*)d_in[14];
    const float* ta_Wk = (const float*)d_in[15]; const float* ta_bk = (const float*)d_in[16];
    const float* ta_Wv = (const float*)d_in[17]; const float* ta_bv = (const float*)d_in[18];
    const float* ta_Wo1 = (const float*)d_in[19]; const float* ta_bo1 = (const float*)d_in[20];
    const float* ta_Wo2 = (const float*)d_in[21]; const float* ta_bo2 = (const float*)d_in[22];
    const float* g_Wxs = (const float*)d_in[23];
    const float* g_Wxt = (const float*)d_in[24]; const float* g_bxt = (const float*)d_in[25];
    const float* g_Wh1 = (const float*)d_in[26]; const float* g_bh1 = (const float*)d_in[27];
    const float* g_Wh2 = (const float*)d_in[28]; const float* g_bh2 = (const float*)d_in[29];

    float* ws = (float*)d_ws;
    float* qs = ws + 0L * P64;
    float* ks = ws + 1L * P64;
    float* vs = ws + 2L * P64;
    float* qt = ws + 3L * P64;
    float* kt = ws + 4L * P64;
    float* vt = ws + 5L * P64;
    // attention outputs alias the q buffers (safe: see kernel comments)
    float* HS = qs;
    float* HT = qt;

    float* out = (float*)d_out;

    hipLaunchKernelGGL(proj_kernel, dim3(PTOT / 8), dim3(64), 0, stream,
                       X, TLE,
                       sa_Wq, sa_bq, sa_Wk, sa_bk, sa_Wv, sa_bv,
                       ta_Wq, ta_bq, ta_Wk, ta_bk, ta_Wv, ta_bv,
                       qs, ks, vs, qt, kt, vt);

    hipLaunchKernelGGL(sattn_kernel, dim3(BB * TT * KH), dim3(128), 0, stream,
                       qs, ks, vs, HS);

    hipLaunchKernelGGL(tattn_kernel, dim3(BB * NN), dim3(192), 0, stream,
                       qt, kt, vt, kpm, HT);

    hipLaunchKernelGGL(epi_kernel, dim3(PTOT / 8), dim3(64), 0, stream,
                       X, HS, HT,
                       sa_Wo1, sa_bo1, sa_Wo2, sa_bo2,
                       ta_Wo1, ta_bo1, ta_Wo2, ta_bo2,
                       g_Wxs, g_Wxt, g_bxt,
                       g_Wh1, g_bh1, g_Wh2, g_bh2,
                       out);
}

// Round 4
// 408.320 us; speedup vs baseline: 1.2496x; 1.0297x over previous
//
#include <hip/hip_runtime.h>
#include <math.h>

#define BB 16
#define TT 24
#define NN 128
#define DD 64
#define KH 8
#define DH 8
#define PTOT (BB * TT * NN)   // 49152 positions
#define P64  (PTOT * 64)      // elements per (B,T,N,64) buffer

typedef __attribute__((ext_vector_type(8))) short bf16x8;
typedef __attribute__((ext_vector_type(4))) float f32x4;

__device__ __forceinline__ unsigned short f2bf(float f) {
    unsigned u = __builtin_bit_cast(unsigned, f);
    u = (u + 0x7fffu + ((u >> 16) & 1u)) >> 16;   // round-to-nearest-even
    return (unsigned short)u;
}

// ---------------------------------------------------------------------------
// Kernel 1: fused 6-way QKV projection via bf16 MFMA.
// C_j = relu(XE @ W_j + b_j), XE = [X|TLE] (M=49152, K=192), W_j (192x64), j=0..5.
// Block = 256 thr (4 waves), M-tile = 64.  Grid = PTOT/64 = 768.
// LDS: XE tile as bf16, row-major [64][200] (pad 192->200: 2-way bank alias, free).
// Each wave: caches 4x6 A-frags (mfma_f32_16x16x32_bf16 A layout:
// A[m=lane&15][k=quad*8+jj]), then loops its 6 (j,nt) tiles: gather/convert
// B-frags (B[k=quad*8+jj][n=lane&15]) from L2-hot fp32 weights, 24 MFMAs,
// bias+relu epilogue in C/D layout (col=lane&15, row=quad*4+r).
// ---------------------------------------------------------------------------
__global__ __launch_bounds__(256) void proj_kernel(
    const float* __restrict__ X, const float* __restrict__ TLE,
    const float* __restrict__ W0, const float* __restrict__ b0,
    const float* __restrict__ W1, const float* __restrict__ b1,
    const float* __restrict__ W2, const float* __restrict__ b2,
    const float* __restrict__ W3, const float* __restrict__ b3,
    const float* __restrict__ W4, const float* __restrict__ b4,
    const float* __restrict__ W5, const float* __restrict__ b5,
    float* __restrict__ o0, float* __restrict__ o1, float* __restrict__ o2,
    float* __restrict__ o3, float* __restrict__ o4, float* __restrict__ o5)
{
    __shared__ __align__(16) unsigned short xe[64][200];
    const int tid = threadIdx.x;
    const long p0 = (long)blockIdx.x * 64;

    // ---- stage XE tile (fp32 -> bf16) into LDS ----
    #pragma unroll
    for (int i = 0; i < 48; ++i) {                 // 64*192/256 = 48
        const int idx = tid + i * 256;
        const int m = idx / 192;
        const int k = idx % 192;
        const float v = (k < 64) ? X[(p0 + m) * 64 + k]
                                 : TLE[(p0 + m) * 128 + (k - 64)];
        xe[m][k] = f2bf(v);
    }
    __syncthreads();

    const int w    = tid >> 6;        // wave 0..3
    const int l    = tid & 63;
    const int quad = l >> 4;          // 0..3
    const int l16  = l & 15;

    // ---- cache A fragments: A[mt][kc], lane holds 8 consecutive k ----
    bf16x8 A[4][6];
    #pragma unroll
    for (int mt = 0; mt < 4; ++mt)
        #pragma unroll
        for (int kc = 0; kc < 6; ++kc)
            A[mt][kc] = *reinterpret_cast<const bf16x8*>(
                &xe[mt * 16 + l16][kc * 32 + quad * 8]);

    const float* Ws[6] = {W0, W1, W2, W3, W4, W5};
    const float* bs[6] = {b0, b1, b2, b3, b4, b5};
    float* Os[6] = {o0, o1, o2, o3, o4, o5};

    // ---- each wave: 6 of the 24 (j, nt) tiles ----
    #pragma unroll
    for (int q = 0; q < 6; ++q) {
        const int tile = w * 6 + q;
        const int j  = tile >> 2;     // 0..5
        const int nt = tile & 3;      // 0..3
        const float* __restrict__ Wj = Ws[j];
        const int n = nt * 16 + l16;

        // gather + convert B fragments (lanes 0..15 read consecutive n: coalesced)
        bf16x8 Bf[6];
        #pragma unroll
        for (int kc = 0; kc < 6; ++kc) {
            bf16x8 bb;
            #pragma unroll
            for (int jj = 0; jj < 8; ++jj) {
                const int k = kc * 32 + quad * 8 + jj;
                bb[jj] = (short)f2bf(Wj[k * 64 + n]);
            }
            Bf[kc] = bb;
        }

        f32x4 acc[4];
        #pragma unroll
        for (int mt = 0; mt < 4; ++mt) acc[mt] = (f32x4){0.f, 0.f, 0.f, 0.f};

        #pragma unroll
        for (int kc = 0; kc < 6; ++kc)
            #pragma unroll
            for (int mt = 0; mt < 4; ++mt)
                acc[mt] = __builtin_amdgcn_mfma_f32_16x16x32_bf16(
                    A[mt][kc], Bf[kc], acc[mt], 0, 0, 0);

        const float bias = bs[j][n];
        float* __restrict__ Oj = Os[j];
        #pragma unroll
        for (int mt = 0; mt < 4; ++mt)
            #pragma unroll
            for (int r = 0; r < 4; ++r)
                Oj[(p0 + mt * 16 + quad * 4 + r) * 64 + n] =
                    fmaxf(acc[mt][r] + bias, 0.0f);
    }
}

// ---------------------------------------------------------------------------
// Kernel 2: spatial attention.  One block per (b*t, head), 128 threads = query n.
// Two-pass softmax (max pass, then exp/accumulate pass recomputing dots).
// O may alias Q (each thread writes only the address it itself read).
// ---------------------------------------------------------------------------
__global__ __launch_bounds__(128) void sattn_kernel(
    const float* __restrict__ Q, const float* __restrict__ Kb,
    const float* __restrict__ V, float* __restrict__ O)
{
    __shared__ float kk[NN][DH];
    __shared__ float vv[NN][DH];
    const int n  = threadIdx.x;
    const int h  = blockIdx.x & 7;
    const int bt = blockIdx.x >> 3;
    const long my = ((long)bt * NN + n) * 64 + h * 8;

    float q[8];
    #pragma unroll
    for (int d = 0; d < 8; ++d) q[d] = Q[my + d];
    #pragma unroll
    for (int d = 0; d < 8; ++d) { kk[n][d] = Kb[my + d]; vv[n][d] = V[my + d]; }
    __syncthreads();

    const float scale = 0.35355339059327373f;  // 1/sqrt(8)

    float mx = -1e30f;
    for (int m = 0; m < NN; ++m) {
        float s = 0.0f;
        #pragma unroll
        for (int d = 0; d < 8; ++d) s = fmaf(q[d], kk[m][d], s);
        mx = fmaxf(mx, s * scale);
    }

    float sum = 0.0f;
    float acc[8];
    #pragma unroll
    for (int d = 0; d < 8; ++d) acc[d] = 0.0f;
    for (int m = 0; m < NN; ++m) {
        float s = 0.0f;
        #pragma unroll
        for (int d = 0; d < 8; ++d) s = fmaf(q[d], kk[m][d], s);
        const float e = __expf(s * scale - mx);
        sum += e;
        #pragma unroll
        for (int d = 0; d < 8; ++d) acc[d] = fmaf(e, vv[m][d], acc[d]);
    }
    const float inv = 1.0f / sum;
    #pragma unroll
    for (int d = 0; d < 8; ++d) O[my + d] = acc[d] * inv;
}

// ---------------------------------------------------------------------------
// Kernel 3: temporal attention (causal + key padding).
// One block per (b, n); 192 threads = (head h, query time i).
// ---------------------------------------------------------------------------
__global__ __launch_bounds__(192) void tattn_kernel(
    const float* __restrict__ Q, const float* __restrict__ Kb,
    const float* __restrict__ V, const int* __restrict__ kpm,
    float* __restrict__ O)
{
    __shared__ float kk[KH][TT][DH];
    __shared__ float vv[KH][TT][DH];
    const int tid = threadIdx.x;
    const int n = blockIdx.x & (NN - 1);
    const int b = blockIdx.x >> 7;

    for (int f = tid; f < KH * TT * DH; f += 192) {
        const int h = f / (TT * DH);
        const int r = f % (TT * DH);
        const int j = r / DH;
        const int d = r % DH;
        const long g = (((long)(b * TT + j)) * NN + n) * 64 + h * 8 + d;
        kk[h][j][d] = Kb[g];
        vv[h][j][d] = V[g];
    }

    const int h = tid / TT;
    const int i = tid % TT;
    const long qb = (((long)(b * TT + i)) * NN + n) * 64 + h * 8;
    float q[8];
    #pragma unroll
    for (int d = 0; d < 8; ++d) q[d] = Q[qb + d];
    __syncthreads();

    const int kp = kpm[b];
    const float scale = 0.35355339059327373f;

    float s[TT];
    #pragma unroll
    for (int j = 0; j < TT; ++j) {
        float t = 0.0f;
        #pragma unroll
        for (int d = 0; d < 8; ++d) t = fmaf(q[d], kk[h][j][d], t);
        s[j] = (j <= i && j < kp) ? t * scale : -INFINITY;
    }
    float mx = -INFINITY;
    #pragma unroll
    for (int j = 0; j < TT; ++j) mx = fmaxf(mx, s[j]);

    float sum = 0.0f;
    float acc[8];
    #pragma unroll
    for (int d = 0; d < 8; ++d) acc[d] = 0.0f;
    #pragma unroll
    for (int j = 0; j < TT; ++j) {
        const float e = __expf(s[j] - mx);  // masked -> exp(-inf)=0
        sum += e;
        #pragma unroll
        for (int d = 0; d < 8; ++d) acc[d] = fmaf(e, vv[h][j][d], acc[d]);
    }
    const float inv = 1.0f / sum;
    #pragma unroll
    for (int d = 0; d < 8; ++d) O[qb + d] = acc[d] * inv;
}

// ---------------------------------------------------------------------------
// Kernel 4: epilogue — 2x (dense-relu-dense), gated fusion, dense-relu-dense,
// residual.  One block = 8 positions, 64 threads (thread = channel).
// Each weight load feeds 8 fmas (G-way ILP breaks the serial fma chain).
// GRID MUST BE PTOT/8.
// ---------------------------------------------------------------------------
__global__ __launch_bounds__(64) void epi_kernel(
    const float* __restrict__ X,
    const float* __restrict__ HSa, const float* __restrict__ HTa,
    const float* __restrict__ sWo1, const float* __restrict__ sbo1,
    const float* __restrict__ sWo2, const float* __restrict__ sbo2,
    const float* __restrict__ tWo1, const float* __restrict__ tbo1,
    const float* __restrict__ tWo2, const float* __restrict__ tbo2,
    const float* __restrict__ Wxs, const float* __restrict__ Wxt,
    const float* __restrict__ bxt,
    const float* __restrict__ Wh1, const float* __restrict__ bh1,
    const float* __restrict__ Wh2, const float* __restrict__ bh2,
    float* __restrict__ out)
{
    constexpr int G = 8;
    __shared__ float sA[G][64], sB[G][64], sHS[G][64], sHT[G][64];
    const int c = threadIdx.x;
    const long base = (long)blockIdx.x * G * 64;

    float acc[G];

    // ---- load HSa tile ----
    #pragma unroll
    for (int g = 0; g < G; ++g) sA[g][c] = HSa[base + g * 64 + c];
    __syncthreads();

    // ---- stage 1: sB = relu(sA @ sWo1 + sbo1) ----
    #pragma unroll
    for (int g = 0; g < G; ++g) acc[g] = sbo1[c];
    for (int k = 0; k < 64; ++k) {
        const float w = sWo1[k * 64 + c];
        #pragma unroll
        for (int g = 0; g < G; ++g) acc[g] = fmaf(sA[g][k], w, acc[g]);
    }
    #pragma unroll
    for (int g = 0; g < G; ++g) sB[g][c] = fmaxf(acc[g], 0.0f);
    __syncthreads();   // stage-1 reads of sA done; sB visible

    // ---- stage 2: hs = sB @ sWo2 + sbo2 ; also refill sA with HTa ----
    #pragma unroll
    for (int g = 0; g < G; ++g) acc[g] = sbo2[c];
    for (int k = 0; k < 64; ++k) {
        const float w = sWo2[k * 64 + c];
        #pragma unroll
        for (int g = 0; g < G; ++g) acc[g] = fmaf(sB[g][k], w, acc[g]);
    }
    float hs[G];
    #pragma unroll
    for (int g = 0; g < G; ++g) { hs[g] = acc[g]; sHS[g][c] = acc[g]; }
    #pragma unroll
    for (int g = 0; g < G; ++g) sA[g][c] = HTa[base + g * 64 + c];
    __syncthreads();   // sA(HTa) + sHS visible; stage-2 reads of sB done

    // ---- stage 3: sB = relu(sA @ tWo1 + tbo1) ----
    #pragma unroll
    for (int g = 0; g < G; ++g) acc[g] = tbo1[c];
    for (int k = 0; k < 64; ++k) {
        const float w = tWo1[k * 64 + c];
        #pragma unroll
        for (int g = 0; g < G; ++g) acc[g] = fmaf(sA[g][k], w, acc[g]);
    }
    #pragma unroll
    for (int g = 0; g < G; ++g) sB[g][c] = fmaxf(acc[g], 0.0f);
    __syncthreads();

    // ---- stage 4: ht = sB @ tWo2 + tbo2 ----
    #pragma unroll
    for (int g = 0; g < G; ++g) acc[g] = tbo2[c];
    for (int k = 0; k < 64; ++k) {
        const float w = tWo2[k * 64 + c];
        #pragma unroll
        for (int g = 0; g < G; ++g) acc[g] = fmaf(sB[g][k], w, acc[g]);
    }
    float ht[G];
    #pragma unroll
    for (int g = 0; g < G; ++g) { ht[g] = acc[g]; sHT[g][c] = acc[g]; }
    __syncthreads();   // sHT visible; stage-3/4 reads of sA/sB done

    // ---- gate: z = sigmoid(HS@Wxs + HT@Wxt + bxt); hval = z*hs+(1-z)*ht ----
    #pragma unroll
    for (int g = 0; g < G; ++g) acc[g] = bxt[c];
    for (int k = 0; k < 64; ++k) {
        const float ws = Wxs[k * 64 + c];
        const float wt = Wxt[k * 64 + c];
        #pragma unroll
        for (int g = 0; g < G; ++g) {
            acc[g] = fmaf(sHS[g][k], ws, acc[g]);
            acc[g] = fmaf(sHT[g][k], wt, acc[g]);
        }
    }
    __syncthreads();   // all gate reads of sHS/sHT done before sA overwrite
    #pragma unroll
    for (int g = 0; g < G; ++g) {
        const float z = 1.0f / (1.0f + __expf(-acc[g]));
        sA[g][c] = z * hs[g] + (1.0f - z) * ht[g];
    }
    __syncthreads();

    // ---- stage 5: sB = relu(sA @ Wh1 + bh1) ----
    #pragma unroll
    for (int g = 0; g < G; ++g) acc[g] = bh1[c];
    for (int k = 0; k < 64; ++k) {
        const float w = Wh1[k * 64 + c];
        #pragma unroll
        for (int g = 0; g < G; ++g) acc[g] = fmaf(sA[g][k], w, acc[g]);
    }
    #pragma unroll
    for (int g = 0; g < G; ++g) sB[g][c] = fmaxf(acc[g], 0.0f);
    __syncthreads();

    // ---- stage 6: out = X + sB @ Wh2 + bh2 ----
    #pragma unroll
    for (int g = 0; g < G; ++g) acc[g] = bh2[c];
    for (int k = 0; k < 64; ++k) {
        const float w = Wh2[k * 64 + c];
        #pragma unroll
        for (int g = 0; g < G; ++g) acc[g] = fmaf(sB[g][k], w, acc[g]);
    }
    #pragma unroll
    for (int g = 0; g < G; ++g)
        out[base + g * 64 + c] = X[base + g * 64 + c] + acc[g];
}

// ---------------------------------------------------------------------------
extern "C" void kernel_launch(void* const* d_in, const int* in_sizes, int n_in,
                              void* d_out, int out_size, void* d_ws, size_t ws_size,
                              hipStream_t stream) {
    const float* X   = (const float*)d_in[0];
    const float* TLE = (const float*)d_in[1];
    const int* kpm   = (const int*)d_in[2];

    const float* sa_Wq = (const float*)d_in[3];  const float* sa_bq = (const float*)d_in[4];
    const float* sa_Wk = (const float*)d_in[5];  const float* sa_bk = (const float*)d_in[6];
    const float* sa_Wv = (const float*)d_in[7];  const float* sa_bv = (const float*)d_in[8];
    const float* sa_Wo1 = (const float*)d_in[9];  const float* sa_bo1 = (const float*)d_in[10];
    const float* sa_Wo2 = (const float*)d_in[11]; const float* sa_bo2 = (const float*)d_in[12];
    const float* ta_Wq = (const float*)d_in[13]; const float* ta_bq = (const float*)d_in[14];
    const float* ta_Wk = (const float*)d_in[15]; const float* ta_bk = (const float*)d_in[16];
    const float* ta_Wv = (const float*)d_in[17]; const float* ta_bv = (const float*)d_in[18];
    const float* ta_Wo1 = (const float*)d_in[19]; const float* ta_bo1 = (const float*)d_in[20];
    const float* ta_Wo2 = (const float*)d_in[21]; const float* ta_bo2 = (const float*)d_in[22];
    const float* g_Wxs = (const float*)d_in[23];
    const float* g_Wxt = (const float*)d_in[24]; const float* g_bxt = (const float*)d_in[25];
    const float* g_Wh1 = (const float*)d_in[26]; const float* g_bh1 = (const float*)d_in[27];
    const float* g_Wh2 = (const float*)d_in[28]; const float* g_bh2 = (const float*)d_in[29];

    float* ws = (float*)d_ws;
    float* qs = ws + 0L * P64;
    float* ks = ws + 1L * P64;
    float* vs = ws + 2L * P64;
    float* qt = ws + 3L * P64;
    float* kt = ws + 4L * P64;
    float* vt = ws + 5L * P64;
    // attention outputs alias the q buffers (safe: see kernel comments)
    float* HS = qs;
    float* HT = qt;

    float* out = (float*)d_out;

    hipLaunchKernelGGL(proj_kernel, dim3(PTOT / 64), dim3(256), 0, stream,
                       X, TLE,
                       sa_Wq, sa_bq, sa_Wk, sa_bk, sa_Wv, sa_bv,
                       ta_Wq, ta_bq, ta_Wk, ta_bk, ta_Wv, ta_bv,
                       qs, ks, vs, qt, kt, vt);

    hipLaunchKernelGGL(sattn_kernel, dim3(BB * TT * KH), dim3(128), 0, stream,
                       qs, ks, vs, HS);

    hipLaunchKernelGGL(tattn_kernel, dim3(BB * NN), dim3(192), 0, stream,
                       qt, kt, vt, kpm, HT);

    hipLaunchKernelGGL(epi_kernel, dim3(PTOT / 8), dim3(64), 0, stream,
                       X, HS, HT,
                       sa_Wo1, sa_bo1, sa_Wo2, sa_bo2,
                       ta_Wo1, ta_bo1, ta_Wo2, ta_bo2,
                       g_Wxs, g_Wxt, g_bxt,
                       g_Wh1, g_bh1, g_Wh2, g_bh2,
                       out);
}

// Round 5
// 319.680 us; speedup vs baseline: 1.5961x; 1.2773x over previous
//
#include <hip/hip_runtime.h>
#include <math.h>

#define BB 16
#define TT 24
#define NN 128
#define DD 64
#define KH 8
#define DH 8
#define PTOT (BB * TT * NN)   // 49152 positions
#define P64  (PTOT * 64)      // elements per (B,T,N,64) buffer

typedef __attribute__((ext_vector_type(8))) short bf16x8;
typedef __attribute__((ext_vector_type(4))) float f32x4;

__device__ __forceinline__ unsigned short f2bf(float f) {
    unsigned u = __builtin_bit_cast(unsigned, f);
    u = (u + 0x7fffu + ((u >> 16) & 1u)) >> 16;   // round-to-nearest-even
    return (unsigned short)u;
}

// ---------------------------------------------------------------------------
// Kernel 0: weight prep — convert 6 proj weights (192x64 fp32, k-major) to
// bf16 transposed [n][k] layout (64x192) so proj can load B-frags as bf16x8.
// Wt layout: [j][n][k], j<6, n<64, k<192.
// ---------------------------------------------------------------------------
__global__ __launch_bounds__(256) void wprep_kernel(
    const float* __restrict__ W0, const float* __restrict__ W1,
    const float* __restrict__ W2, const float* __restrict__ W3,
    const float* __restrict__ W4, const float* __restrict__ W5,
    unsigned short* __restrict__ Wt)
{
    const float* Ws[6] = {W0, W1, W2, W3, W4, W5};
    const int e = blockIdx.x * 256 + threadIdx.x;   // < 6*192*64 = 73728
    const int j = e / 12288;
    const int r = e % 12288;
    const int k = r / 64;
    const int n = r % 64;
    Wt[j * 12288 + n * 192 + k] = f2bf(Ws[j][k * 64 + n]);
}

// ---------------------------------------------------------------------------
// Kernel 1: fused 6-way QKV projection via bf16 MFMA, swapped operands.
// D' = W^T (M-dim = channel) x XE^T (N-dim = position): C/D layout then gives
// each lane 4 CONSECUTIVE channels for one position -> coalesced float4 stores.
// Block = 256 thr (4 waves), 64 positions.  Grid = PTOT/64 = 768.
// ---------------------------------------------------------------------------
__global__ __launch_bounds__(256) void proj_kernel(
    const float* __restrict__ X, const float* __restrict__ TLE,
    const unsigned short* __restrict__ Wt,   // [6][64][192] bf16
    const float* __restrict__ b0, const float* __restrict__ b1,
    const float* __restrict__ b2, const float* __restrict__ b3,
    const float* __restrict__ b4, const float* __restrict__ b5,
    float* __restrict__ o0, float* __restrict__ o1, float* __restrict__ o2,
    float* __restrict__ o3, float* __restrict__ o4, float* __restrict__ o5)
{
    __shared__ __align__(16) unsigned short xe[64][200];  // [m][k] bf16, pad 192->200
    const int tid = threadIdx.x;
    const long p0 = (long)blockIdx.x * 64;

    // ---- stage XE tile (fp32 -> bf16) into LDS: float4 loads, ushort4 writes ----
    #pragma unroll
    for (int i = 0; i < 12; ++i) {                 // 64*48 float4s / 256 thr
        const int idx4 = tid + i * 256;
        const int m  = idx4 / 48;
        const int kq = idx4 % 48;                  // float4 index within row
        const int k  = kq * 4;
        float4 v;
        if (k < 64) v = *reinterpret_cast<const float4*>(X + (p0 + m) * 64 + k);
        else        v = *reinterpret_cast<const float4*>(TLE + (p0 + m) * 128 + (k - 64));
        ushort4 pk;
        pk.x = f2bf(v.x); pk.y = f2bf(v.y); pk.z = f2bf(v.z); pk.w = f2bf(v.w);
        *reinterpret_cast<ushort4*>(&xe[m][k]) = pk;
    }
    __syncthreads();

    const int w    = tid >> 6;        // wave 0..3
    const int l    = tid & 63;
    const int quad = l >> 4;          // 0..3
    const int l16  = l & 15;

    // ---- cache XE^T fragments (the MFMA B operand: lane&15 = position) ----
    bf16x8 xef[4][6];
    #pragma unroll
    for (int mt = 0; mt < 4; ++mt)
        #pragma unroll
        for (int kc = 0; kc < 6; ++kc)
            xef[mt][kc] = *reinterpret_cast<const bf16x8*>(
                &xe[mt * 16 + l16][kc * 32 + quad * 8]);

    const float* bs[6] = {b0, b1, b2, b3, b4, b5};
    float* Os[6] = {o0, o1, o2, o3, o4, o5};

    // ---- each wave: 6 of the 24 (j, nt) tiles ----
    #pragma unroll
    for (int q = 0; q < 6; ++q) {
        const int tile = w * 6 + q;
        const int j  = tile >> 2;     // weight matrix 0..5
        const int nt = tile & 3;      // channel tile 0..3
        const unsigned short* __restrict__ Wj = Wt + j * 12288;
        const int n_loc = nt * 16 + l16;

        // W^T fragments (MFMA A operand: lane&15 = channel, 8 consecutive k)
        bf16x8 wf[6];
        #pragma unroll
        for (int kc = 0; kc < 6; ++kc)
            wf[kc] = *reinterpret_cast<const bf16x8*>(
                &Wj[n_loc * 192 + kc * 32 + quad * 8]);

        f32x4 acc[4];
        #pragma unroll
        for (int mt = 0; mt < 4; ++mt) acc[mt] = (f32x4){0.f, 0.f, 0.f, 0.f};

        #pragma unroll
        for (int kc = 0; kc < 6; ++kc)
            #pragma unroll
            for (int mt = 0; mt < 4; ++mt)
                acc[mt] = __builtin_amdgcn_mfma_f32_16x16x32_bf16(
                    wf[kc], xef[mt][kc], acc[mt], 0, 0, 0);

        // epilogue: lane holds channels nt*16+quad*4..+3 of position mt*16+l16
        const float4 b4 = *reinterpret_cast<const float4*>(&bs[j][nt * 16 + quad * 4]);
        float* __restrict__ Oj = Os[j];
        #pragma unroll
        for (int mt = 0; mt < 4; ++mt) {
            float4 o;
            o.x = fmaxf(acc[mt][0] + b4.x, 0.0f);
            o.y = fmaxf(acc[mt][1] + b4.y, 0.0f);
            o.z = fmaxf(acc[mt][2] + b4.z, 0.0f);
            o.w = fmaxf(acc[mt][3] + b4.w, 0.0f);
            *reinterpret_cast<float4*>(
                &Oj[(p0 + mt * 16 + l16) * 64 + nt * 16 + quad * 4]) = o;
        }
    }
}

// ---------------------------------------------------------------------------
// Kernel 2: spatial attention.  One block per (b*t, head), 128 threads = query n.
// ---------------------------------------------------------------------------
__global__ __launch_bounds__(128) void sattn_kernel(
    const float* __restrict__ Q, const float* __restrict__ Kb,
    const float* __restrict__ V, float* __restrict__ O)
{
    __shared__ float kk[NN][DH];
    __shared__ float vv[NN][DH];
    const int n  = threadIdx.x;
    const int h  = blockIdx.x & 7;
    const int bt = blockIdx.x >> 3;
    const long my = ((long)bt * NN + n) * 64 + h * 8;

    float q[8];
    #pragma unroll
    for (int d = 0; d < 8; ++d) q[d] = Q[my + d];
    #pragma unroll
    for (int d = 0; d < 8; ++d) { kk[n][d] = Kb[my + d]; vv[n][d] = V[my + d]; }
    __syncthreads();

    const float scale = 0.35355339059327373f;  // 1/sqrt(8)

    float mx = -1e30f;
    for (int m = 0; m < NN; ++m) {
        float s = 0.0f;
        #pragma unroll
        for (int d = 0; d < 8; ++d) s = fmaf(q[d], kk[m][d], s);
        mx = fmaxf(mx, s * scale);
    }

    float sum = 0.0f;
    float acc[8];
    #pragma unroll
    for (int d = 0; d < 8; ++d) acc[d] = 0.0f;
    for (int m = 0; m < NN; ++m) {
        float s = 0.0f;
        #pragma unroll
        for (int d = 0; d < 8; ++d) s = fmaf(q[d], kk[m][d], s);
        const float e = __expf(s * scale - mx);
        sum += e;
        #pragma unroll
        for (int d = 0; d < 8; ++d) acc[d] = fmaf(e, vv[m][d], acc[d]);
    }
    const float inv = 1.0f / sum;
    #pragma unroll
    for (int d = 0; d < 8; ++d) O[my + d] = acc[d] * inv;
}

// ---------------------------------------------------------------------------
// Kernel 3: temporal attention (causal + key padding).
// One block per (b, n); 192 threads = (head h, query time i).
// ---------------------------------------------------------------------------
__global__ __launch_bounds__(192) void tattn_kernel(
    const float* __restrict__ Q, const float* __restrict__ Kb,
    const float* __restrict__ V, const int* __restrict__ kpm,
    float* __restrict__ O)
{
    __shared__ float kk[KH][TT][DH];
    __shared__ float vv[KH][TT][DH];
    const int tid = threadIdx.x;
    const int n = blockIdx.x & (NN - 1);
    const int b = blockIdx.x >> 7;

    for (int f = tid; f < KH * TT * DH; f += 192) {
        const int h = f / (TT * DH);
        const int r = f % (TT * DH);
        const int j = r / DH;
        const int d = r % DH;
        const long g = (((long)(b * TT + j)) * NN + n) * 64 + h * 8 + d;
        kk[h][j][d] = Kb[g];
        vv[h][j][d] = V[g];
    }

    const int h = tid / TT;
    const int i = tid % TT;
    const long qb = (((long)(b * TT + i)) * NN + n) * 64 + h * 8;
    float q[8];
    #pragma unroll
    for (int d = 0; d < 8; ++d) q[d] = Q[qb + d];
    __syncthreads();

    const int kp = kpm[b];
    const float scale = 0.35355339059327373f;

    float s[TT];
    #pragma unroll
    for (int j = 0; j < TT; ++j) {
        float t = 0.0f;
        #pragma unroll
        for (int d = 0; d < 8; ++d) t = fmaf(q[d], kk[h][j][d], t);
        s[j] = (j <= i && j < kp) ? t * scale : -INFINITY;
    }
    float mx = -INFINITY;
    #pragma unroll
    for (int j = 0; j < TT; ++j) mx = fmaxf(mx, s[j]);

    float sum = 0.0f;
    float acc[8];
    #pragma unroll
    for (int d = 0; d < 8; ++d) acc[d] = 0.0f;
    #pragma unroll
    for (int j = 0; j < TT; ++j) {
        const float e = __expf(s[j] - mx);  // masked -> exp(-inf)=0
        sum += e;
        #pragma unroll
        for (int d = 0; d < 8; ++d) acc[d] = fmaf(e, vv[h][j][d], acc[d]);
    }
    const float inv = 1.0f / sum;
    #pragma unroll
    for (int d = 0; d < 8; ++d) O[qb + d] = acc[d] * inv;
}

// ---------------------------------------------------------------------------
// Kernel 4: epilogue.  One block = 8 positions, 64 threads (thread = channel).
// Activations in TRANSPOSED LDS layout sAT[ch][g] (row pad 12 keeps 16B align)
// so each k-iter reads the 8 broadcast values as 2x ds_read_b128.
// GRID MUST BE PTOT/8.
// ---------------------------------------------------------------------------
__global__ __launch_bounds__(64) void epi_kernel(
    const float* __restrict__ X,
    const float* __restrict__ HSa, const float* __restrict__ HTa,
    const float* __restrict__ sWo1, const float* __restrict__ sbo1,
    const float* __restrict__ sWo2, const float* __restrict__ sbo2,
    const float* __restrict__ tWo1, const float* __restrict__ tbo1,
    const float* __restrict__ tWo2, const float* __restrict__ tbo2,
    const float* __restrict__ Wxs, const float* __restrict__ Wxt,
    const float* __restrict__ bxt,
    const float* __restrict__ Wh1, const float* __restrict__ bh1,
    const float* __restrict__ Wh2, const float* __restrict__ bh2,
    float* __restrict__ out)
{
    constexpr int G = 8;
    constexpr int RS = 12;   // row stride (floats): 48B -> b128-aligned rows
    __shared__ __align__(16) float sAT[64][RS], sBT[64][RS], sHST[64][RS], sHTT[64][RS];
    const int c = threadIdx.x;
    const long base = (long)blockIdx.x * G * 64;

    float acc[G];

    // helper macros for the transposed access pattern
#define READ8(arr, k, dst)                                            \
    { const float4 lo = *reinterpret_cast<const float4*>(&arr[k][0]); \
      const float4 hi = *reinterpret_cast<const float4*>(&arr[k][4]); \
      dst[0]=lo.x; dst[1]=lo.y; dst[2]=lo.z; dst[3]=lo.w;             \
      dst[4]=hi.x; dst[5]=hi.y; dst[6]=hi.z; dst[7]=hi.w; }
#define WRITE8(arr, vals)                                              \
    { float4 lo, hi;                                                   \
      lo.x=vals[0]; lo.y=vals[1]; lo.z=vals[2]; lo.w=vals[3];          \
      hi.x=vals[4]; hi.y=vals[5]; hi.z=vals[6]; hi.w=vals[7];          \
      *reinterpret_cast<float4*>(&sAT_dummy_##arr[c][0]) = lo;         \
      *reinterpret_cast<float4*>(&sAT_dummy_##arr[c][4]) = hi; }

    float v8[G];

    // ---- load HSa tile (thread c gathers channel c of 8 positions) ----
    #pragma unroll
    for (int g = 0; g < G; ++g) v8[g] = HSa[base + g * 64 + c];
    { float4 lo = {v8[0],v8[1],v8[2],v8[3]}, hi = {v8[4],v8[5],v8[6],v8[7]};
      *reinterpret_cast<float4*>(&sAT[c][0]) = lo;
      *reinterpret_cast<float4*>(&sAT[c][4]) = hi; }
    __syncthreads();

    // ---- stage 1: sBT = relu(A @ sWo1 + sbo1) ----
    #pragma unroll
    for (int g = 0; g < G; ++g) acc[g] = sbo1[c];
    for (int k = 0; k < 64; ++k) {
        const float w = sWo1[k * 64 + c];
        float a[G]; READ8(sAT, k, a);
        #pragma unroll
        for (int g = 0; g < G; ++g) acc[g] = fmaf(a[g], w, acc[g]);
    }
    { float4 lo = {fmaxf(acc[0],0.f),fmaxf(acc[1],0.f),fmaxf(acc[2],0.f),fmaxf(acc[3],0.f)};
      float4 hi = {fmaxf(acc[4],0.f),fmaxf(acc[5],0.f),fmaxf(acc[6],0.f),fmaxf(acc[7],0.f)};
      *reinterpret_cast<float4*>(&sBT[c][0]) = lo;
      *reinterpret_cast<float4*>(&sBT[c][4]) = hi; }
    __syncthreads();

    // ---- stage 2: hs = B @ sWo2 + sbo2 ; refill sAT with HTa ----
    #pragma unroll
    for (int g = 0; g < G; ++g) acc[g] = sbo2[c];
    for (int k = 0; k < 64; ++k) {
        const float w = sWo2[k * 64 + c];
        float a[G]; READ8(sBT, k, a);
        #pragma unroll
        for (int g = 0; g < G; ++g) acc[g] = fmaf(a[g], w, acc[g]);
    }
    float hs[G];
    #pragma unroll
    for (int g = 0; g < G; ++g) hs[g] = acc[g];
    { float4 lo = {acc[0],acc[1],acc[2],acc[3]}, hi = {acc[4],acc[5],acc[6],acc[7]};
      *reinterpret_cast<float4*>(&sHST[c][0]) = lo;
      *reinterpret_cast<float4*>(&sHST[c][4]) = hi; }
    #pragma unroll
    for (int g = 0; g < G; ++g) v8[g] = HTa[base + g * 64 + c];
    { float4 lo = {v8[0],v8[1],v8[2],v8[3]}, hi = {v8[4],v8[5],v8[6],v8[7]};
      *reinterpret_cast<float4*>(&sAT[c][0]) = lo;
      *reinterpret_cast<float4*>(&sAT[c][4]) = hi; }
    __syncthreads();

    // ---- stage 3: sBT = relu(A @ tWo1 + tbo1) ----
    #pragma unroll
    for (int g = 0; g < G; ++g) acc[g] = tbo1[c];
    for (int k = 0; k < 64; ++k) {
        const float w = tWo1[k * 64 + c];
        float a[G]; READ8(sAT, k, a);
        #pragma unroll
        for (int g = 0; g < G; ++g) acc[g] = fmaf(a[g], w, acc[g]);
    }
    { float4 lo = {fmaxf(acc[0],0.f),fmaxf(acc[1],0.f),fmaxf(acc[2],0.f),fmaxf(acc[3],0.f)};
      float4 hi = {fmaxf(acc[4],0.f),fmaxf(acc[5],0.f),fmaxf(acc[6],0.f),fmaxf(acc[7],0.f)};
      *reinterpret_cast<float4*>(&sBT[c][0]) = lo;
      *reinterpret_cast<float4*>(&sBT[c][4]) = hi; }
    __syncthreads();

    // ---- stage 4: ht = B @ tWo2 + tbo2 ----
    #pragma unroll
    for (int g = 0; g < G; ++g) acc[g] = tbo2[c];
    for (int k = 0; k < 64; ++k) {
        const float w = tWo2[k * 64 + c];
        float a[G]; READ8(sBT, k, a);
        #pragma unroll
        for (int g = 0; g < G; ++g) acc[g] = fmaf(a[g], w, acc[g]);
    }
    float ht[G];
    #pragma unroll
    for (int g = 0; g < G; ++g) ht[g] = acc[g];
    { float4 lo = {acc[0],acc[1],acc[2],acc[3]}, hi = {acc[4],acc[5],acc[6],acc[7]};
      *reinterpret_cast<float4*>(&sHTT[c][0]) = lo;
      *reinterpret_cast<float4*>(&sHTT[c][4]) = hi; }
    __syncthreads();

    // ---- gate ----
    #pragma unroll
    for (int g = 0; g < G; ++g) acc[g] = bxt[c];
    for (int k = 0; k < 64; ++k) {
        const float ws = Wxs[k * 64 + c];
        const float wt = Wxt[k * 64 + c];
        float a[G]; READ8(sHST, k, a);
        float b[G]; READ8(sHTT, k, b);
        #pragma unroll
        for (int g = 0; g < G; ++g) {
            acc[g] = fmaf(a[g], ws, acc[g]);
            acc[g] = fmaf(b[g], wt, acc[g]);
        }
    }
    __syncthreads();   // gate reads done before sAT overwrite
    #pragma unroll
    for (int g = 0; g < G; ++g) {
        const float z = 1.0f / (1.0f + __expf(-acc[g]));
        v8[g] = z * hs[g] + (1.0f - z) * ht[g];
    }
    { float4 lo = {v8[0],v8[1],v8[2],v8[3]}, hi = {v8[4],v8[5],v8[6],v8[7]};
      *reinterpret_cast<float4*>(&sAT[c][0]) = lo;
      *reinterpret_cast<float4*>(&sAT[c][4]) = hi; }
    __syncthreads();

    // ---- stage 5: sBT = relu(A @ Wh1 + bh1) ----
    #pragma unroll
    for (int g = 0; g < G; ++g) acc[g] = bh1[c];
    for (int k = 0; k < 64; ++k) {
        const float w = Wh1[k * 64 + c];
        float a[G]; READ8(sAT, k, a);
        #pragma unroll
        for (int g = 0; g < G; ++g) acc[g] = fmaf(a[g], w, acc[g]);
    }
    { float4 lo = {fmaxf(acc[0],0.f),fmaxf(acc[1],0.f),fmaxf(acc[2],0.f),fmaxf(acc[3],0.f)};
      float4 hi = {fmaxf(acc[4],0.f),fmaxf(acc[5],0.f),fmaxf(acc[6],0.f),fmaxf(acc[7],0.f)};
      *reinterpret_cast<float4*>(&sBT[c][0]) = lo;
      *reinterpret_cast<float4*>(&sBT[c][4]) = hi; }
    __syncthreads();

    // ---- stage 6: out = X + B @ Wh2 + bh2 ----
    #pragma unroll
    for (int g = 0; g < G; ++g) acc[g] = bh2[c];
    for (int k = 0; k < 64; ++k) {
        const float w = Wh2[k * 64 + c];
        float a[G]; READ8(sBT, k, a);
        #pragma unroll
        for (int g = 0; g < G; ++g) acc[g] = fmaf(a[g], w, acc[g]);
    }
    #pragma unroll
    for (int g = 0; g < G; ++g)
        out[base + g * 64 + c] = X[base + g * 64 + c] + acc[g];
#undef READ8
#undef WRITE8
}

// ---------------------------------------------------------------------------
extern "C" void kernel_launch(void* const* d_in, const int* in_sizes, int n_in,
                              void* d_out, int out_size, void* d_ws, size_t ws_size,
                              hipStream_t stream) {
    const float* X   = (const float*)d_in[0];
    const float* TLE = (const float*)d_in[1];
    const int* kpm   = (const int*)d_in[2];

    const float* sa_Wq = (const float*)d_in[3];  const float* sa_bq = (const float*)d_in[4];
    const float* sa_Wk = (const float*)d_in[5];  const float* sa_bk = (const float*)d_in[6];
    const float* sa_Wv = (const float*)d_in[7];  const float* sa_bv = (const float*)d_in[8];
    const float* sa_Wo1 = (const float*)d_in[9];  const float* sa_bo1 = (const float*)d_in[10];
    const float* sa_Wo2 = (const float*)d_in[11]; const float* sa_bo2 = (const float*)d_in[12];
    const float* ta_Wq = (const float*)d_in[13]; const float* ta_bq = (const float*)d_in[14];
    const float* ta_Wk = (const float*)d_in[15]; const float* ta_bk = (const float*)d_in[16];
    const float* ta_Wv = (const float*)d_in[17]; const float* ta_bv = (const float*)d_in[18];
    const float* ta_Wo1 = (const float*)d_in[19]; const float* ta_bo1 = (const float*)d_in[20];
    const float* ta_Wo2 = (const float*)d_in[21]; const float* ta_bo2 = (const float*)d_in[22];
    const float* g_Wxs = (const float*)d_in[23];
    const float* g_Wxt = (const float*)d_in[24]; const float* g_bxt = (const float*)d_in[25];
    const float* g_Wh1 = (const float*)d_in[26]; const float* g_bh1 = (const float*)d_in[27];
    const float* g_Wh2 = (const float*)d_in[28]; const float* g_bh2 = (const float*)d_in[29];

    float* ws = (float*)d_ws;
    float* qs = ws + 0L * P64;
    float* ks = ws + 1L * P64;
    float* vs = ws + 2L * P64;
    float* qt = ws + 3L * P64;
    float* kt = ws + 4L * P64;
    float* vt = ws + 5L * P64;
    unsigned short* Wt = (unsigned short*)(ws + 6L * P64);  // 6*64*192 bf16
    // attention outputs alias the q buffers (safe: see kernel comments)
    float* HS = qs;
    float* HT = qt;

    float* out = (float*)d_out;

    hipLaunchKernelGGL(wprep_kernel, dim3(288), dim3(256), 0, stream,
                       sa_Wq, sa_Wk, sa_Wv, ta_Wq, ta_Wk, ta_Wv, Wt);

    hipLaunchKernelGGL(proj_kernel, dim3(PTOT / 64), dim3(256), 0, stream,
                       X, TLE, Wt,
                       sa_bq, sa_bk, sa_bv, ta_bq, ta_bk, ta_bv,
                       qs, ks, vs, qt, kt, vt);

    hipLaunchKernelGGL(sattn_kernel, dim3(BB * TT * KH), dim3(128), 0, stream,
                       qs, ks, vs, HS);

    hipLaunchKernelGGL(tattn_kernel, dim3(BB * NN), dim3(192), 0, stream,
                       qt, kt, vt, kpm, HT);

    hipLaunchKernelGGL(epi_kernel, dim3(PTOT / 8), dim3(64), 0, stream,
                       X, HS, HT,
                       sa_Wo1, sa_bo1, sa_Wo2, sa_bo2,
                       ta_Wo1, ta_bo1, ta_Wo2, ta_bo2,
                       g_Wxs, g_Wxt, g_bxt,
                       g_Wh1, g_bh1, g_Wh2, g_bh2,
                       out);
}

// Round 6
// 274.449 us; speedup vs baseline: 1.8591x; 1.1648x over previous
//
#include <hip/hip_runtime.h>
#include <math.h>

#define BB 16
#define TT 24
#define NN 128
#define DD 64
#define KH 8
#define DH 8
#define PTOT (BB * TT * NN)   // 49152 positions
#define P64  (PTOT * 64)      // elements per (B,T,N,64) buffer

typedef __attribute__((ext_vector_type(8))) short bf16x8;
typedef __attribute__((ext_vector_type(4))) float f32x4;

__device__ __forceinline__ unsigned short f2bf(float f) {
    unsigned u = __builtin_bit_cast(unsigned, f);
    u = (u + 0x7fffu + ((u >> 16) & 1u)) >> 16;   // round-to-nearest-even
    return (unsigned short)u;
}

// ---------------------------------------------------------------------------
// Kernel 0a: proj weight prep — 6x (192x64 fp32, k-major) -> bf16 [j][n][k].
// ---------------------------------------------------------------------------
__global__ __launch_bounds__(256) void wprep_kernel(
    const float* __restrict__ W0, const float* __restrict__ W1,
    const float* __restrict__ W2, const float* __restrict__ W3,
    const float* __restrict__ W4, const float* __restrict__ W5,
    unsigned short* __restrict__ Wt)
{
    const float* Ws[6] = {W0, W1, W2, W3, W4, W5};
    const int e = blockIdx.x * 256 + threadIdx.x;   // < 6*192*64 = 73728
    const int j = e / 12288;
    const int r = e % 12288;
    const int k = r / 64;
    const int n = r % 64;
    Wt[j * 12288 + n * 192 + k] = f2bf(Ws[j][k * 64 + n]);
}

// ---------------------------------------------------------------------------
// Kernel 0b: epi weight prep — 8x (64x64 fp32, k-major) -> bf16 [mat][n][k].
// mat order: sWo1, sWo2, tWo1, tWo2, Wxs, Wxt, Wh1, Wh2.
// ---------------------------------------------------------------------------
__global__ __launch_bounds__(256) void wprep8_kernel(
    const float* __restrict__ W0, const float* __restrict__ W1,
    const float* __restrict__ W2, const float* __restrict__ W3,
    const float* __restrict__ W4, const float* __restrict__ W5,
    const float* __restrict__ W6, const float* __restrict__ W7,
    unsigned short* __restrict__ Wt8)
{
    const float* Ws[8] = {W0, W1, W2, W3, W4, W5, W6, W7};
    const int e = blockIdx.x * 256 + threadIdx.x;   // < 8*4096 = 32768
    const int mat = e >> 12;
    const int r = e & 4095;
    const int k = r >> 6;
    const int n = r & 63;
    Wt8[mat * 4096 + n * 64 + k] = f2bf(Ws[mat][k * 64 + n]);
}

// ---------------------------------------------------------------------------
// Kernel 1: fused 6-way QKV projection via bf16 MFMA, swapped operands.
// Block = 256 thr (4 waves), 64 positions.  Grid = PTOT/64 = 768.
// ---------------------------------------------------------------------------
__global__ __launch_bounds__(256) void proj_kernel(
    const float* __restrict__ X, const float* __restrict__ TLE,
    const unsigned short* __restrict__ Wt,   // [6][64][192] bf16
    const float* __restrict__ b0, const float* __restrict__ b1,
    const float* __restrict__ b2, const float* __restrict__ b3,
    const float* __restrict__ b4, const float* __restrict__ b5,
    float* __restrict__ o0, float* __restrict__ o1, float* __restrict__ o2,
    float* __restrict__ o3, float* __restrict__ o4, float* __restrict__ o5)
{
    __shared__ __align__(16) unsigned short xe[64][200];  // [m][k] bf16
    const int tid = threadIdx.x;
    const long p0 = (long)blockIdx.x * 64;

    #pragma unroll
    for (int i = 0; i < 12; ++i) {                 // 64*48 float4s / 256 thr
        const int idx4 = tid + i * 256;
        const int m  = idx4 / 48;
        const int kq = idx4 % 48;
        const int k  = kq * 4;
        float4 v;
        if (k < 64) v = *reinterpret_cast<const float4*>(X + (p0 + m) * 64 + k);
        else        v = *reinterpret_cast<const float4*>(TLE + (p0 + m) * 128 + (k - 64));
        ushort4 pk;
        pk.x = f2bf(v.x); pk.y = f2bf(v.y); pk.z = f2bf(v.z); pk.w = f2bf(v.w);
        *reinterpret_cast<ushort4*>(&xe[m][k]) = pk;
    }
    __syncthreads();

    const int w    = tid >> 6;
    const int l    = tid & 63;
    const int quad = l >> 4;
    const int l16  = l & 15;

    bf16x8 xef[4][6];
    #pragma unroll
    for (int mt = 0; mt < 4; ++mt)
        #pragma unroll
        for (int kc = 0; kc < 6; ++kc)
            xef[mt][kc] = *reinterpret_cast<const bf16x8*>(
                &xe[mt * 16 + l16][kc * 32 + quad * 8]);

    const float* bs[6] = {b0, b1, b2, b3, b4, b5};
    float* Os[6] = {o0, o1, o2, o3, o4, o5};

    #pragma unroll
    for (int q = 0; q < 6; ++q) {
        const int tile = w * 6 + q;
        const int j  = tile >> 2;
        const int nt = tile & 3;
        const unsigned short* __restrict__ Wj = Wt + j * 12288;
        const int n_loc = nt * 16 + l16;

        bf16x8 wf[6];
        #pragma unroll
        for (int kc = 0; kc < 6; ++kc)
            wf[kc] = *reinterpret_cast<const bf16x8*>(
                &Wj[n_loc * 192 + kc * 32 + quad * 8]);

        f32x4 acc[4];
        #pragma unroll
        for (int mt = 0; mt < 4; ++mt) acc[mt] = (f32x4){0.f, 0.f, 0.f, 0.f};

        #pragma unroll
        for (int kc = 0; kc < 6; ++kc)
            #pragma unroll
            for (int mt = 0; mt < 4; ++mt)
                acc[mt] = __builtin_amdgcn_mfma_f32_16x16x32_bf16(
                    wf[kc], xef[mt][kc], acc[mt], 0, 0, 0);

        const float4 b4 = *reinterpret_cast<const float4*>(&bs[j][nt * 16 + quad * 4]);
        float* __restrict__ Oj = Os[j];
        #pragma unroll
        for (int mt = 0; mt < 4; ++mt) {
            float4 o;
            o.x = fmaxf(acc[mt][0] + b4.x, 0.0f);
            o.y = fmaxf(acc[mt][1] + b4.y, 0.0f);
            o.z = fmaxf(acc[mt][2] + b4.z, 0.0f);
            o.w = fmaxf(acc[mt][3] + b4.w, 0.0f);
            *reinterpret_cast<float4*>(
                &Oj[(p0 + mt * 16 + l16) * 64 + nt * 16 + quad * 4]) = o;
        }
    }
}

// ---------------------------------------------------------------------------
// Kernel 2: spatial attention.  One block per (b*t, head), 128 threads = query n.
// ---------------------------------------------------------------------------
__global__ __launch_bounds__(128) void sattn_kernel(
    const float* __restrict__ Q, const float* __restrict__ Kb,
    const float* __restrict__ V, float* __restrict__ O)
{
    __shared__ float kk[NN][DH];
    __shared__ float vv[NN][DH];
    const int n  = threadIdx.x;
    const int h  = blockIdx.x & 7;
    const int bt = blockIdx.x >> 3;
    const long my = ((long)bt * NN + n) * 64 + h * 8;

    float q[8];
    #pragma unroll
    for (int d = 0; d < 8; ++d) q[d] = Q[my + d];
    #pragma unroll
    for (int d = 0; d < 8; ++d) { kk[n][d] = Kb[my + d]; vv[n][d] = V[my + d]; }
    __syncthreads();

    const float scale = 0.35355339059327373f;  // 1/sqrt(8)

    float mx = -1e30f;
    for (int m = 0; m < NN; ++m) {
        float s = 0.0f;
        #pragma unroll
        for (int d = 0; d < 8; ++d) s = fmaf(q[d], kk[m][d], s);
        mx = fmaxf(mx, s * scale);
    }

    float sum = 0.0f;
    float acc[8];
    #pragma unroll
    for (int d = 0; d < 8; ++d) acc[d] = 0.0f;
    for (int m = 0; m < NN; ++m) {
        float s = 0.0f;
        #pragma unroll
        for (int d = 0; d < 8; ++d) s = fmaf(q[d], kk[m][d], s);
        const float e = __expf(s * scale - mx);
        sum += e;
        #pragma unroll
        for (int d = 0; d < 8; ++d) acc[d] = fmaf(e, vv[m][d], acc[d]);
    }
    const float inv = 1.0f / sum;
    #pragma unroll
    for (int d = 0; d < 8; ++d) O[my + d] = acc[d] * inv;
}

// ---------------------------------------------------------------------------
// Kernel 3: temporal attention (causal + key padding).
// One block per (b, n); 192 threads = (head h, query time i).
// ---------------------------------------------------------------------------
__global__ __launch_bounds__(192) void tattn_kernel(
    const float* __restrict__ Q, const float* __restrict__ Kb,
    const float* __restrict__ V, const int* __restrict__ kpm,
    float* __restrict__ O)
{
    __shared__ float kk[KH][TT][DH];
    __shared__ float vv[KH][TT][DH];
    const int tid = threadIdx.x;
    const int n = blockIdx.x & (NN - 1);
    const int b = blockIdx.x >> 7;

    for (int f = tid; f < KH * TT * DH; f += 192) {
        const int h = f / (TT * DH);
        const int r = f % (TT * DH);
        const int j = r / DH;
        const int d = r % DH;
        const long g = (((long)(b * TT + j)) * NN + n) * 64 + h * 8 + d;
        kk[h][j][d] = Kb[g];
        vv[h][j][d] = V[g];
    }

    const int h = tid / TT;
    const int i = tid % TT;
    const long qb = (((long)(b * TT + i)) * NN + n) * 64 + h * 8;
    float q[8];
    #pragma unroll
    for (int d = 0; d < 8; ++d) q[d] = Q[qb + d];
    __syncthreads();

    const int kp = kpm[b];
    const float scale = 0.35355339059327373f;

    float s[TT];
    #pragma unroll
    for (int j = 0; j < TT; ++j) {
        float t = 0.0f;
        #pragma unroll
        for (int d = 0; d < 8; ++d) t = fmaf(q[d], kk[h][j][d], t);
        s[j] = (j <= i && j < kp) ? t * scale : -INFINITY;
    }
    float mx = -INFINITY;
    #pragma unroll
    for (int j = 0; j < TT; ++j) mx = fmaxf(mx, s[j]);

    float sum = 0.0f;
    float acc[8];
    #pragma unroll
    for (int d = 0; d < 8; ++d) acc[d] = 0.0f;
    #pragma unroll
    for (int j = 0; j < TT; ++j) {
        const float e = __expf(s[j] - mx);  // masked -> exp(-inf)=0
        sum += e;
        #pragma unroll
        for (int d = 0; d < 8; ++d) acc[d] = fmaf(e, vv[h][j][d], acc[d]);
    }
    const float inv = 1.0f / sum;
    #pragma unroll
    for (int d = 0; d < 8; ++d) O[qb + d] = acc[d] * inv;
}

// ---------------------------------------------------------------------------
// Kernel 4: epilogue via bf16 MFMA, swapped operands (same scheme as proj).
// Block = 256 thr (4 waves), 64-position tile.  Grid = PTOT/64 = 768.
// 8 GEMMs (64x64x64) ping-ponged through 3 bf16 LDS buffers [pos][ch],
// row stride 72 shorts (even bank spread for ds_read_b128).
// Gate/sigmoid/residual kept fp32 in registers.
// ---------------------------------------------------------------------------
__global__ __launch_bounds__(256) void epi_kernel(
    const float* __restrict__ X,
    const float* __restrict__ HSa, const float* __restrict__ HTa,
    const unsigned short* __restrict__ Wt8,  // [8][64][64] bf16
    const float* __restrict__ sbo1, const float* __restrict__ sbo2,
    const float* __restrict__ tbo1, const float* __restrict__ tbo2,
    const float* __restrict__ bxt,
    const float* __restrict__ bh1, const float* __restrict__ bh2,
    float* __restrict__ out)
{
    constexpr int RS = 72;
    __shared__ __align__(16) unsigned short bufA[64][RS], bufB[64][RS], bufC[64][RS];
    const int tid = threadIdx.x;
    const long p0 = (long)blockIdx.x * 64;
    const int w = tid >> 6, l = tid & 63, quad = l >> 4, l16 = l & 15;
    const int chBase = w * 16 + quad * 4;    // 4 consecutive output channels

    // ---- stage HSa -> bufA, HTa -> bufC ----
    #pragma unroll
    for (int i = 0; i < 4; ++i) {
        const int idx = tid + i * 256;      // < 1024
        const int m = idx >> 4;
        const int c = (idx & 15) * 4;
        float4 v = *reinterpret_cast<const float4*>(HSa + (p0 + m) * 64 + c);
        ushort4 pk; pk.x = f2bf(v.x); pk.y = f2bf(v.y); pk.z = f2bf(v.z); pk.w = f2bf(v.w);
        *reinterpret_cast<ushort4*>(&bufA[m][c]) = pk;
        float4 u = *reinterpret_cast<const float4*>(HTa + (p0 + m) * 64 + c);
        ushort4 qk; qk.x = f2bf(u.x); qk.y = f2bf(u.y); qk.z = f2bf(u.z); qk.w = f2bf(u.w);
        *reinterpret_cast<ushort4*>(&bufC[m][c]) = qk;
    }
    __syncthreads();

    // gemm: D'[ch][pos] = W^T x Act^T ; acc[pt] covers pos pt*16+l16, ch chBase..+3
    auto gemm = [&](const unsigned short (*in)[RS], int mat,
                    const float* __restrict__ bias, f32x4* accO) {
        bf16x8 af[2];
        #pragma unroll
        for (int kc = 0; kc < 2; ++kc)
            af[kc] = *reinterpret_cast<const bf16x8*>(
                &Wt8[mat * 4096 + (w * 16 + l16) * 64 + kc * 32 + quad * 8]);
        const float4 b4 = *reinterpret_cast<const float4*>(&bias[chBase]);
        #pragma unroll
        for (int pt = 0; pt < 4; ++pt) {
            f32x4 acc = (f32x4){0.f, 0.f, 0.f, 0.f};
            #pragma unroll
            for (int kc = 0; kc < 2; ++kc) {
                bf16x8 bf = *reinterpret_cast<const bf16x8*>(
                    &in[pt * 16 + l16][kc * 32 + quad * 8]);
                acc = __builtin_amdgcn_mfma_f32_16x16x32_bf16(af[kc], bf, acc, 0, 0, 0);
            }
            acc[0] += b4.x; acc[1] += b4.y; acc[2] += b4.z; acc[3] += b4.w;
            accO[pt] = acc;
        }
    };

    auto writeBuf = [&](unsigned short (*dst)[RS], const f32x4* v, bool relu) {
        #pragma unroll
        for (int pt = 0; pt < 4; ++pt) {
            float a0 = v[pt][0], a1 = v[pt][1], a2 = v[pt][2], a3 = v[pt][3];
            if (relu) { a0 = fmaxf(a0, 0.f); a1 = fmaxf(a1, 0.f);
                        a2 = fmaxf(a2, 0.f); a3 = fmaxf(a3, 0.f); }
            ushort4 pk; pk.x = f2bf(a0); pk.y = f2bf(a1); pk.z = f2bf(a2); pk.w = f2bf(a3);
            *reinterpret_cast<ushort4*>(&dst[pt * 16 + l16][chBase]) = pk;
        }
    };

    f32x4 t[4], HSr[4], HTr[4];

    gemm(bufA, 0, sbo1, t);                 // HS1 = relu(HSa@sWo1+b)
    __syncthreads();
    writeBuf(bufB, t, true);
    __syncthreads();

    gemm(bufB, 1, sbo2, HSr);               // HS (fp32 regs)
    __syncthreads();
    writeBuf(bufA, HSr, false);             // HS bf16
    __syncthreads();

    gemm(bufC, 2, tbo1, t);                 // HT1 = relu(HTa@tWo1+b)
    __syncthreads();
    writeBuf(bufB, t, true);
    __syncthreads();

    gemm(bufB, 3, tbo2, HTr);               // HT (fp32 regs)
    __syncthreads();
    writeBuf(bufC, HTr, false);             // HT bf16
    __syncthreads();

    // ---- gate: z = sigmoid(HS@Wxs + HT@Wxt + bxt); H = z*HS+(1-z)*HT ----
    {
        bf16x8 afS[2], afT[2];
        #pragma unroll
        for (int kc = 0; kc < 2; ++kc) {
            afS[kc] = *reinterpret_cast<const bf16x8*>(
                &Wt8[4 * 4096 + (w * 16 + l16) * 64 + kc * 32 + quad * 8]);
            afT[kc] = *reinterpret_cast<const bf16x8*>(
                &Wt8[5 * 4096 + (w * 16 + l16) * 64 + kc * 32 + quad * 8]);
        }
        const float4 b4 = *reinterpret_cast<const float4*>(&bxt[chBase]);
        #pragma unroll
        for (int pt = 0; pt < 4; ++pt) {
            f32x4 acc = (f32x4){0.f, 0.f, 0.f, 0.f};
            #pragma unroll
            for (int kc = 0; kc < 2; ++kc) {
                bf16x8 hsf = *reinterpret_cast<const bf16x8*>(
                    &bufA[pt * 16 + l16][kc * 32 + quad * 8]);
                acc = __builtin_amdgcn_mfma_f32_16x16x32_bf16(afS[kc], hsf, acc, 0, 0, 0);
            }
            #pragma unroll
            for (int kc = 0; kc < 2; ++kc) {
                bf16x8 htf = *reinterpret_cast<const bf16x8*>(
                    &bufC[pt * 16 + l16][kc * 32 + quad * 8]);
                acc = __builtin_amdgcn_mfma_f32_16x16x32_bf16(afT[kc], htf, acc, 0, 0, 0);
            }
            const float zb[4] = {acc[0] + b4.x, acc[1] + b4.y, acc[2] + b4.z, acc[3] + b4.w};
            f32x4 h;
            #pragma unroll
            for (int r = 0; r < 4; ++r) {
                const float z = 1.0f / (1.0f + __expf(-zb[r]));
                h[r] = z * HSr[pt][r] + (1.0f - z) * HTr[pt][r];
            }
            t[pt] = h;
        }
    }
    __syncthreads();
    writeBuf(bufB, t, false);               // H bf16
    __syncthreads();

    gemm(bufB, 6, bh1, t);                  // H1 = relu(H@Wh1+b)
    __syncthreads();
    writeBuf(bufA, t, true);
    __syncthreads();

    gemm(bufA, 7, bh2, t);                  // out = X + H1@Wh2+b
    #pragma unroll
    for (int pt = 0; pt < 4; ++pt) {
        const long pos = p0 + pt * 16 + l16;
        const float4 xv = *reinterpret_cast<const float4*>(&X[pos * 64 + chBase]);
        float4 o;
        o.x = t[pt][0] + xv.x; o.y = t[pt][1] + xv.y;
        o.z = t[pt][2] + xv.z; o.w = t[pt][3] + xv.w;
        *reinterpret_cast<float4*>(&out[pos * 64 + chBase]) = o;
    }
}

// ---------------------------------------------------------------------------
extern "C" void kernel_launch(void* const* d_in, const int* in_sizes, int n_in,
                              void* d_out, int out_size, void* d_ws, size_t ws_size,
                              hipStream_t stream) {
    const float* X   = (const float*)d_in[0];
    const float* TLE = (const float*)d_in[1];
    const int* kpm   = (const int*)d_in[2];

    const float* sa_Wq = (const float*)d_in[3];  const float* sa_bq = (const float*)d_in[4];
    const float* sa_Wk = (const float*)d_in[5];  const float* sa_bk = (const float*)d_in[6];
    const float* sa_Wv = (const float*)d_in[7];  const float* sa_bv = (const float*)d_in[8];
    const float* sa_Wo1 = (const float*)d_in[9];  const float* sa_bo1 = (const float*)d_in[10];
    const float* sa_Wo2 = (const float*)d_in[11]; const float* sa_bo2 = (const float*)d_in[12];
    const float* ta_Wq = (const float*)d_in[13]; const float* ta_bq = (const float*)d_in[14];
    const float* ta_Wk = (const float*)d_in[15]; const float* ta_bk = (const float*)d_in[16];
    const float* ta_Wv = (const float*)d_in[17]; const float* ta_bv = (const float*)d_in[18];
    const float* ta_Wo1 = (const float*)d_in[19]; const float* ta_bo1 = (const float*)d_in[20];
    const float* ta_Wo2 = (const float*)d_in[21]; const float* ta_bo2 = (const float*)d_in[22];
    const float* g_Wxs = (const float*)d_in[23];
    const float* g_Wxt = (const float*)d_in[24]; const float* g_bxt = (const float*)d_in[25];
    const float* g_Wh1 = (const float*)d_in[26]; const float* g_bh1 = (const float*)d_in[27];
    const float* g_Wh2 = (const float*)d_in[28]; const float* g_bh2 = (const float*)d_in[29];

    float* ws = (float*)d_ws;
    float* qs = ws + 0L * P64;
    float* ks = ws + 1L * P64;
    float* vs = ws + 2L * P64;
    float* qt = ws + 3L * P64;
    float* kt = ws + 4L * P64;
    float* vt = ws + 5L * P64;
    unsigned short* Wt  = (unsigned short*)(ws + 6L * P64);  // 6*64*192 bf16
    unsigned short* Wt8 = Wt + 6 * 12288;                    // 8*64*64 bf16
    // attention outputs alias the q buffers (safe: per-thread read-then-write)
    float* HS = qs;
    float* HT = qt;

    float* out = (float*)d_out;

    hipLaunchKernelGGL(wprep_kernel, dim3(288), dim3(256), 0, stream,
                       sa_Wq, sa_Wk, sa_Wv, ta_Wq, ta_Wk, ta_Wv, Wt);

    hipLaunchKernelGGL(wprep8_kernel, dim3(128), dim3(256), 0, stream,
                       sa_Wo1, sa_Wo2, ta_Wo1, ta_Wo2, g_Wxs, g_Wxt, g_Wh1, g_Wh2,
                       Wt8);

    hipLaunchKernelGGL(proj_kernel, dim3(PTOT / 64), dim3(256), 0, stream,
                       X, TLE, Wt,
                       sa_bq, sa_bk, sa_bv, ta_bq, ta_bk, ta_bv,
                       qs, ks, vs, qt, kt, vt);

    hipLaunchKernelGGL(sattn_kernel, dim3(BB * TT * KH), dim3(128), 0, stream,
                       qs, ks, vs, HS);

    hipLaunchKernelGGL(tattn_kernel, dim3(BB * NN), dim3(192), 0, stream,
                       qt, kt, vt, kpm, HT);

    hipLaunchKernelGGL(epi_kernel, dim3(PTOT / 64), dim3(256), 0, stream,
                       X, HS, HT, Wt8,
                       sa_bo1, sa_bo2, ta_bo1, ta_bo2, g_bxt, g_bh1, g_bh2,
                       out);
}

// Round 7
// 251.365 us; speedup vs baseline: 2.0299x; 1.0918x over previous
//
#include <hip/hip_runtime.h>
#include <math.h>

#define BB 16
#define TT 24
#define NN 128
#define DD 64
#define KH 8
#define DH 8
#define PTOT (BB * TT * NN)   // 49152 positions
#define P64  (PTOT * 64)      // elements per (B,T,N,64) buffer

typedef __attribute__((ext_vector_type(8))) short bf16x8;
typedef __attribute__((ext_vector_type(4))) float f32x4;

__device__ __forceinline__ unsigned short f2bf(float f) {
    unsigned u = __builtin_bit_cast(unsigned, f);
    u = (u + 0x7fffu + ((u >> 16) & 1u)) >> 16;   // round-to-nearest-even
    return (unsigned short)u;
}

// ---------------------------------------------------------------------------
// Kernel 0a: proj weight prep — 6x (192x64 fp32, k-major) -> bf16 [j][n][k].
// ---------------------------------------------------------------------------
__global__ __launch_bounds__(256) void wprep_kernel(
    const float* __restrict__ W0, const float* __restrict__ W1,
    const float* __restrict__ W2, const float* __restrict__ W3,
    const float* __restrict__ W4, const float* __restrict__ W5,
    unsigned short* __restrict__ Wt)
{
    const float* Ws[6] = {W0, W1, W2, W3, W4, W5};
    const int e = blockIdx.x * 256 + threadIdx.x;   // < 6*192*64 = 73728
    const int j = e / 12288;
    const int r = e % 12288;
    const int k = r / 64;
    const int n = r % 64;
    Wt[j * 12288 + n * 192 + k] = f2bf(Ws[j][k * 64 + n]);
}

// ---------------------------------------------------------------------------
// Kernel 0b: epi weight prep — 8x (64x64 fp32, k-major) -> bf16 [mat][n][k].
// mat order: sWo1, sWo2, tWo1, tWo2, Wxs, Wxt, Wh1, Wh2.
// ---------------------------------------------------------------------------
__global__ __launch_bounds__(256) void wprep8_kernel(
    const float* __restrict__ W0, const float* __restrict__ W1,
    const float* __restrict__ W2, const float* __restrict__ W3,
    const float* __restrict__ W4, const float* __restrict__ W5,
    const float* __restrict__ W6, const float* __restrict__ W7,
    unsigned short* __restrict__ Wt8)
{
    const float* Ws[8] = {W0, W1, W2, W3, W4, W5, W6, W7};
    const int e = blockIdx.x * 256 + threadIdx.x;   // < 8*4096 = 32768
    const int mat = e >> 12;
    const int r = e & 4095;
    const int k = r >> 6;
    const int n = r & 63;
    Wt8[mat * 4096 + n * 64 + k] = f2bf(Ws[mat][k * 64 + n]);
}

// ---------------------------------------------------------------------------
// Kernel 1: fused 6-way QKV projection via bf16 MFMA, swapped operands.
// Block = 256 thr (4 waves), 64 positions.  Grid = PTOT/64 = 768.
// ---------------------------------------------------------------------------
__global__ __launch_bounds__(256) void proj_kernel(
    const float* __restrict__ X, const float* __restrict__ TLE,
    const unsigned short* __restrict__ Wt,   // [6][64][192] bf16
    const float* __restrict__ b0, const float* __restrict__ b1,
    const float* __restrict__ b2, const float* __restrict__ b3,
    const float* __restrict__ b4, const float* __restrict__ b5,
    float* __restrict__ o0, float* __restrict__ o1, float* __restrict__ o2,
    float* __restrict__ o3, float* __restrict__ o4, float* __restrict__ o5)
{
    __shared__ __align__(16) unsigned short xe[64][200];  // [m][k] bf16
    const int tid = threadIdx.x;
    const long p0 = (long)blockIdx.x * 64;

    #pragma unroll
    for (int i = 0; i < 12; ++i) {                 // 64*48 float4s / 256 thr
        const int idx4 = tid + i * 256;
        const int m  = idx4 / 48;
        const int kq = idx4 % 48;
        const int k  = kq * 4;
        float4 v;
        if (k < 64) v = *reinterpret_cast<const float4*>(X + (p0 + m) * 64 + k);
        else        v = *reinterpret_cast<const float4*>(TLE + (p0 + m) * 128 + (k - 64));
        ushort4 pk;
        pk.x = f2bf(v.x); pk.y = f2bf(v.y); pk.z = f2bf(v.z); pk.w = f2bf(v.w);
        *reinterpret_cast<ushort4*>(&xe[m][k]) = pk;
    }
    __syncthreads();

    const int w    = tid >> 6;
    const int l    = tid & 63;
    const int quad = l >> 4;
    const int l16  = l & 15;

    bf16x8 xef[4][6];
    #pragma unroll
    for (int mt = 0; mt < 4; ++mt)
        #pragma unroll
        for (int kc = 0; kc < 6; ++kc)
            xef[mt][kc] = *reinterpret_cast<const bf16x8*>(
                &xe[mt * 16 + l16][kc * 32 + quad * 8]);

    const float* bs[6] = {b0, b1, b2, b3, b4, b5};
    float* Os[6] = {o0, o1, o2, o3, o4, o5};

    #pragma unroll
    for (int q = 0; q < 6; ++q) {
        const int tile = w * 6 + q;
        const int j  = tile >> 2;
        const int nt = tile & 3;
        const unsigned short* __restrict__ Wj = Wt + j * 12288;
        const int n_loc = nt * 16 + l16;

        bf16x8 wf[6];
        #pragma unroll
        for (int kc = 0; kc < 6; ++kc)
            wf[kc] = *reinterpret_cast<const bf16x8*>(
                &Wj[n_loc * 192 + kc * 32 + quad * 8]);

        f32x4 acc[4];
        #pragma unroll
        for (int mt = 0; mt < 4; ++mt) acc[mt] = (f32x4){0.f, 0.f, 0.f, 0.f};

        #pragma unroll
        for (int kc = 0; kc < 6; ++kc)
            #pragma unroll
            for (int mt = 0; mt < 4; ++mt)
                acc[mt] = __builtin_amdgcn_mfma_f32_16x16x32_bf16(
                    wf[kc], xef[mt][kc], acc[mt], 0, 0, 0);

        const float4 b4 = *reinterpret_cast<const float4*>(&bs[j][nt * 16 + quad * 4]);
        float* __restrict__ Oj = Os[j];
        #pragma unroll
        for (int mt = 0; mt < 4; ++mt) {
            float4 o;
            o.x = fmaxf(acc[mt][0] + b4.x, 0.0f);
            o.y = fmaxf(acc[mt][1] + b4.y, 0.0f);
            o.z = fmaxf(acc[mt][2] + b4.z, 0.0f);
            o.w = fmaxf(acc[mt][3] + b4.w, 0.0f);
            *reinterpret_cast<float4*>(
                &Oj[(p0 + mt * 16 + l16) * 64 + nt * 16 + quad * 4]) = o;
        }
    }
}

// ---------------------------------------------------------------------------
// Kernel 2: spatial attention, restructured.
// One block per (b,t): 256 threads = (head h = tid>>5, 4 query rows each).
// K/V staged once as straight fp32 copy (natural layout, conflict-free).
// Single-pass softmax WITHOUT max subtraction: inputs are relu'd projections,
// s*scale <= ~5 realistically (fp32 exp overflows at 88) — mathematically
// identical to the max-subtracted form.  scale folded into q at load.
// O aliases Q: thread reads its own q rows before the barrier, writes the
// same addresses at the end — no cross-thread overlap.
// ---------------------------------------------------------------------------
__global__ __launch_bounds__(256) void sattn_kernel(
    const float* __restrict__ Q, const float* __restrict__ Kb,
    const float* __restrict__ V, float* __restrict__ O)
{
    __shared__ __align__(16) float kk[NN][DD];   // 32 KB
    __shared__ __align__(16) float vv[NN][DD];   // 32 KB
    const int tid = threadIdx.x;
    const long base = (long)blockIdx.x * NN * DD;

    // ---- stage K,V (straight copy, coalesced, conflict-free) ----
    #pragma unroll
    for (int i = 0; i < 8; ++i) {
        const int idx4 = tid + i * 256;          // < 2048 float4s
        *reinterpret_cast<float4*>(&kk[0][0] + idx4 * 4) =
            *reinterpret_cast<const float4*>(Kb + base + idx4 * 4);
        *reinterpret_cast<float4*>(&vv[0][0] + idx4 * 4) =
            *reinterpret_cast<const float4*>(V + base + idx4 * 4);
    }

    const int h  = tid >> 5;          // head 0..7
    const int r0 = tid & 31;          // base query row
    const float scale = 0.35355339059327373f;  // 1/sqrt(8)

    // ---- load 4 q rows, pre-scaled ----
    float q[4][8];
    #pragma unroll
    for (int r = 0; r < 4; ++r) {
        const int row = r0 + r * 32;
        const float4 a = *reinterpret_cast<const float4*>(Q + base + row * 64 + h * 8);
        const float4 b = *reinterpret_cast<const float4*>(Q + base + row * 64 + h * 8 + 4);
        q[r][0] = a.x * scale; q[r][1] = a.y * scale;
        q[r][2] = a.z * scale; q[r][3] = a.w * scale;
        q[r][4] = b.x * scale; q[r][5] = b.y * scale;
        q[r][6] = b.z * scale; q[r][7] = b.w * scale;
    }
    __syncthreads();

    float sum[4] = {0.f, 0.f, 0.f, 0.f};
    float acc[4][8];
    #pragma unroll
    for (int r = 0; r < 4; ++r)
        #pragma unroll
        for (int d = 0; d < 8; ++d) acc[r][d] = 0.f;

    for (int m = 0; m < NN; ++m) {
        const float4 ka = *reinterpret_cast<const float4*>(&kk[m][h * 8]);
        const float4 kb = *reinterpret_cast<const float4*>(&kk[m][h * 8 + 4]);
        const float4 va = *reinterpret_cast<const float4*>(&vv[m][h * 8]);
        const float4 vb = *reinterpret_cast<const float4*>(&vv[m][h * 8 + 4]);
        #pragma unroll
        for (int r = 0; r < 4; ++r) {
            float s = q[r][0] * ka.x;
            s = fmaf(q[r][1], ka.y, s);
            s = fmaf(q[r][2], ka.z, s);
            s = fmaf(q[r][3], ka.w, s);
            s = fmaf(q[r][4], kb.x, s);
            s = fmaf(q[r][5], kb.y, s);
            s = fmaf(q[r][6], kb.z, s);
            s = fmaf(q[r][7], kb.w, s);
            const float e = __expf(s);
            sum[r] += e;
            acc[r][0] = fmaf(e, va.x, acc[r][0]);
            acc[r][1] = fmaf(e, va.y, acc[r][1]);
            acc[r][2] = fmaf(e, va.z, acc[r][2]);
            acc[r][3] = fmaf(e, va.w, acc[r][3]);
            acc[r][4] = fmaf(e, vb.x, acc[r][4]);
            acc[r][5] = fmaf(e, vb.y, acc[r][5]);
            acc[r][6] = fmaf(e, vb.z, acc[r][6]);
            acc[r][7] = fmaf(e, vb.w, acc[r][7]);
        }
    }

    #pragma unroll
    for (int r = 0; r < 4; ++r) {
        const int row = r0 + r * 32;
        const float inv = 1.0f / sum[r];
        float4 oa, ob;
        oa.x = acc[r][0] * inv; oa.y = acc[r][1] * inv;
        oa.z = acc[r][2] * inv; oa.w = acc[r][3] * inv;
        ob.x = acc[r][4] * inv; ob.y = acc[r][5] * inv;
        ob.z = acc[r][6] * inv; ob.w = acc[r][7] * inv;
        *reinterpret_cast<float4*>(O + base + row * 64 + h * 8)     = oa;
        *reinterpret_cast<float4*>(O + base + row * 64 + h * 8 + 4) = ob;
    }
}

// ---------------------------------------------------------------------------
// Kernel 3: temporal attention (causal + key padding).
// One block per (b, n); 192 threads = (head h, query time i).
// ---------------------------------------------------------------------------
__global__ __launch_bounds__(192) void tattn_kernel(
    const float* __restrict__ Q, const float* __restrict__ Kb,
    const float* __restrict__ V, const int* __restrict__ kpm,
    float* __restrict__ O)
{
    __shared__ float kk[KH][TT][DH];
    __shared__ float vv[KH][TT][DH];
    const int tid = threadIdx.x;
    const int n = blockIdx.x & (NN - 1);
    const int b = blockIdx.x >> 7;

    for (int f = tid; f < KH * TT * DH; f += 192) {
        const int h = f / (TT * DH);
        const int r = f % (TT * DH);
        const int j = r / DH;
        const int d = r % DH;
        const long g = (((long)(b * TT + j)) * NN + n) * 64 + h * 8 + d;
        kk[h][j][d] = Kb[g];
        vv[h][j][d] = V[g];
    }

    const int h = tid / TT;
    const int i = tid % TT;
    const long qb = (((long)(b * TT + i)) * NN + n) * 64 + h * 8;
    float q[8];
    #pragma unroll
    for (int d = 0; d < 8; ++d) q[d] = Q[qb + d];
    __syncthreads();

    const int kp = kpm[b];
    const float scale = 0.35355339059327373f;

    float s[TT];
    #pragma unroll
    for (int j = 0; j < TT; ++j) {
        float t = 0.0f;
        #pragma unroll
        for (int d = 0; d < 8; ++d) t = fmaf(q[d], kk[h][j][d], t);
        s[j] = (j <= i && j < kp) ? t * scale : -INFINITY;
    }
    float mx = -INFINITY;
    #pragma unroll
    for (int j = 0; j < TT; ++j) mx = fmaxf(mx, s[j]);

    float sum = 0.0f;
    float acc[8];
    #pragma unroll
    for (int d = 0; d < 8; ++d) acc[d] = 0.0f;
    #pragma unroll
    for (int j = 0; j < TT; ++j) {
        const float e = __expf(s[j] - mx);  // masked -> exp(-inf)=0
        sum += e;
        #pragma unroll
        for (int d = 0; d < 8; ++d) acc[d] = fmaf(e, vv[h][j][d], acc[d]);
    }
    const float inv = 1.0f / sum;
    #pragma unroll
    for (int d = 0; d < 8; ++d) O[qb + d] = acc[d] * inv;
}

// ---------------------------------------------------------------------------
// Kernel 4: epilogue via bf16 MFMA, swapped operands (same scheme as proj).
// Block = 256 thr (4 waves), 64-position tile.  Grid = PTOT/64 = 768.
// ---------------------------------------------------------------------------
__global__ __launch_bounds__(256) void epi_kernel(
    const float* __restrict__ X,
    const float* __restrict__ HSa, const float* __restrict__ HTa,
    const unsigned short* __restrict__ Wt8,  // [8][64][64] bf16
    const float* __restrict__ sbo1, const float* __restrict__ sbo2,
    const float* __restrict__ tbo1, const float* __restrict__ tbo2,
    const float* __restrict__ bxt,
    const float* __restrict__ bh1, const float* __restrict__ bh2,
    float* __restrict__ out)
{
    constexpr int RS = 72;
    __shared__ __align__(16) unsigned short bufA[64][RS], bufB[64][RS], bufC[64][RS];
    const int tid = threadIdx.x;
    const long p0 = (long)blockIdx.x * 64;
    const int w = tid >> 6, l = tid & 63, quad = l >> 4, l16 = l & 15;
    const int chBase = w * 16 + quad * 4;    // 4 consecutive output channels

    // ---- stage HSa -> bufA, HTa -> bufC ----
    #pragma unroll
    for (int i = 0; i < 4; ++i) {
        const int idx = tid + i * 256;      // < 1024
        const int m = idx >> 4;
        const int c = (idx & 15) * 4;
        float4 v = *reinterpret_cast<const float4*>(HSa + (p0 + m) * 64 + c);
        ushort4 pk; pk.x = f2bf(v.x); pk.y = f2bf(v.y); pk.z = f2bf(v.z); pk.w = f2bf(v.w);
        *reinterpret_cast<ushort4*>(&bufA[m][c]) = pk;
        float4 u = *reinterpret_cast<const float4*>(HTa + (p0 + m) * 64 + c);
        ushort4 qk; qk.x = f2bf(u.x); qk.y = f2bf(u.y); qk.z = f2bf(u.z); qk.w = f2bf(u.w);
        *reinterpret_cast<ushort4*>(&bufC[m][c]) = qk;
    }
    __syncthreads();

    auto gemm = [&](const unsigned short (*in)[RS], int mat,
                    const float* __restrict__ bias, f32x4* accO) {
        bf16x8 af[2];
        #pragma unroll
        for (int kc = 0; kc < 2; ++kc)
            af[kc] = *reinterpret_cast<const bf16x8*>(
                &Wt8[mat * 4096 + (w * 16 + l16) * 64 + kc * 32 + quad * 8]);
        const float4 b4 = *reinterpret_cast<const float4*>(&bias[chBase]);
        #pragma unroll
        for (int pt = 0; pt < 4; ++pt) {
            f32x4 acc = (f32x4){0.f, 0.f, 0.f, 0.f};
            #pragma unroll
            for (int kc = 0; kc < 2; ++kc) {
                bf16x8 bf = *reinterpret_cast<const bf16x8*>(
                    &in[pt * 16 + l16][kc * 32 + quad * 8]);
                acc = __builtin_amdgcn_mfma_f32_16x16x32_bf16(af[kc], bf, acc, 0, 0, 0);
            }
            acc[0] += b4.x; acc[1] += b4.y; acc[2] += b4.z; acc[3] += b4.w;
            accO[pt] = acc;
        }
    };

    auto writeBuf = [&](unsigned short (*dst)[RS], const f32x4* v, bool relu) {
        #pragma unroll
        for (int pt = 0; pt < 4; ++pt) {
            float a0 = v[pt][0], a1 = v[pt][1], a2 = v[pt][2], a3 = v[pt][3];
            if (relu) { a0 = fmaxf(a0, 0.f); a1 = fmaxf(a1, 0.f);
                        a2 = fmaxf(a2, 0.f); a3 = fmaxf(a3, 0.f); }
            ushort4 pk; pk.x = f2bf(a0); pk.y = f2bf(a1); pk.z = f2bf(a2); pk.w = f2bf(a3);
            *reinterpret_cast<ushort4*>(&dst[pt * 16 + l16][chBase]) = pk;
        }
    };

    f32x4 t[4], HSr[4], HTr[4];

    gemm(bufA, 0, sbo1, t);                 // HS1 = relu(HSa@sWo1+b)
    __syncthreads();
    writeBuf(bufB, t, true);
    __syncthreads();

    gemm(bufB, 1, sbo2, HSr);               // HS (fp32 regs)
    __syncthreads();
    writeBuf(bufA, HSr, false);             // HS bf16
    __syncthreads();

    gemm(bufC, 2, tbo1, t);                 // HT1 = relu(HTa@tWo1+b)
    __syncthreads();
    writeBuf(bufB, t, true);
    __syncthreads();

    gemm(bufB, 3, tbo2, HTr);               // HT (fp32 regs)
    __syncthreads();
    writeBuf(bufC, HTr, false);             // HT bf16
    __syncthreads();

    // ---- gate ----
    {
        bf16x8 afS[2], afT[2];
        #pragma unroll
        for (int kc = 0; kc < 2; ++kc) {
            afS[kc] = *reinterpret_cast<const bf16x8*>(
                &Wt8[4 * 4096 + (w * 16 + l16) * 64 + kc * 32 + quad * 8]);
            afT[kc] = *reinterpret_cast<const bf16x8*>(
                &Wt8[5 * 4096 + (w * 16 + l16) * 64 + kc * 32 + quad * 8]);
        }
        const float4 b4 = *reinterpret_cast<const float4*>(&bxt[chBase]);
        #pragma unroll
        for (int pt = 0; pt < 4; ++pt) {
            f32x4 acc = (f32x4){0.f, 0.f, 0.f, 0.f};
            #pragma unroll
            for (int kc = 0; kc < 2; ++kc) {
                bf16x8 hsf = *reinterpret_cast<const bf16x8*>(
                    &bufA[pt * 16 + l16][kc * 32 + quad * 8]);
                acc = __builtin_amdgcn_mfma_f32_16x16x32_bf16(afS[kc], hsf, acc, 0, 0, 0);
            }
            #pragma unroll
            for (int kc = 0; kc < 2; ++kc) {
                bf16x8 htf = *reinterpret_cast<const bf16x8*>(
                    &bufC[pt * 16 + l16][kc * 32 + quad * 8]);
                acc = __builtin_amdgcn_mfma_f32_16x16x32_bf16(afT[kc], htf, acc, 0, 0, 0);
            }
            const float zb[4] = {acc[0] + b4.x, acc[1] + b4.y, acc[2] + b4.z, acc[3] + b4.w};
            f32x4 h;
            #pragma unroll
            for (int r = 0; r < 4; ++r) {
                const float z = 1.0f / (1.0f + __expf(-zb[r]));
                h[r] = z * HSr[pt][r] + (1.0f - z) * HTr[pt][r];
            }
            t[pt] = h;
        }
    }
    __syncthreads();
    writeBuf(bufB, t, false);               // H bf16
    __syncthreads();

    gemm(bufB, 6, bh1, t);                  // H1 = relu(H@Wh1+b)
    __syncthreads();
    writeBuf(bufA, t, true);
    __syncthreads();

    gemm(bufA, 7, bh2, t);                  // out = X + H1@Wh2+b
    #pragma unroll
    for (int pt = 0; pt < 4; ++pt) {
        const long pos = p0 + pt * 16 + l16;
        const float4 xv = *reinterpret_cast<const float4*>(&X[pos * 64 + chBase]);
        float4 o;
        o.x = t[pt][0] + xv.x; o.y = t[pt][1] + xv.y;
        o.z = t[pt][2] + xv.z; o.w = t[pt][3] + xv.w;
        *reinterpret_cast<float4*>(&out[pos * 64 + chBase]) = o;
    }
}

// ---------------------------------------------------------------------------
extern "C" void kernel_launch(void* const* d_in, const int* in_sizes, int n_in,
                              void* d_out, int out_size, void* d_ws, size_t ws_size,
                              hipStream_t stream) {
    const float* X   = (const float*)d_in[0];
    const float* TLE = (const float*)d_in[1];
    const int* kpm   = (const int*)d_in[2];

    const float* sa_Wq = (const float*)d_in[3];  const float* sa_bq = (const float*)d_in[4];
    const float* sa_Wk = (const float*)d_in[5];  const float* sa_bk = (const float*)d_in[6];
    const float* sa_Wv = (const float*)d_in[7];  const float* sa_bv = (const float*)d_in[8];
    const float* sa_Wo1 = (const float*)d_in[9];  const float* sa_bo1 = (const float*)d_in[10];
    const float* sa_Wo2 = (const float*)d_in[11]; const float* sa_bo2 = (const float*)d_in[12];
    const float* ta_Wq = (const float*)d_in[13]; const float* ta_bq = (const float*)d_in[14];
    const float* ta_Wk = (const float*)d_in[15]; const float* ta_bk = (const float*)d_in[16];
    const float* ta_Wv = (const float*)d_in[17]; const float* ta_bv = (const float*)d_in[18];
    const float* ta_Wo1 = (const float*)d_in[19]; const float* ta_bo1 = (const float*)d_in[20];
    const float* ta_Wo2 = (const float*)d_in[21]; const float* ta_bo2 = (const float*)d_in[22];
    const float* g_Wxs = (const float*)d_in[23];
    const float* g_Wxt = (const float*)d_in[24]; const float* g_bxt = (const float*)d_in[25];
    const float* g_Wh1 = (const float*)d_in[26]; const float* g_bh1 = (const float*)d_in[27];
    const float* g_Wh2 = (const float*)d_in[28]; const float* g_bh2 = (const float*)d_in[29];

    float* ws = (float*)d_ws;
    float* qs = ws + 0L * P64;
    float* ks = ws + 1L * P64;
    float* vs = ws + 2L * P64;
    float* qt = ws + 3L * P64;
    float* kt = ws + 4L * P64;
    float* vt = ws + 5L * P64;
    unsigned short* Wt  = (unsigned short*)(ws + 6L * P64);  // 6*64*192 bf16
    unsigned short* Wt8 = Wt + 6 * 12288;                    // 8*64*64 bf16
    // attention outputs alias the q buffers (safe: per-thread read-then-write)
    float* HS = qs;
    float* HT = qt;

    float* out = (float*)d_out;

    hipLaunchKernelGGL(wprep_kernel, dim3(288), dim3(256), 0, stream,
                       sa_Wq, sa_Wk, sa_Wv, ta_Wq, ta_Wk, ta_Wv, Wt);

    hipLaunchKernelGGL(wprep8_kernel, dim3(128), dim3(256), 0, stream,
                       sa_Wo1, sa_Wo2, ta_Wo1, ta_Wo2, g_Wxs, g_Wxt, g_Wh1, g_Wh2,
                       Wt8);

    hipLaunchKernelGGL(proj_kernel, dim3(PTOT / 64), dim3(256), 0, stream,
                       X, TLE, Wt,
                       sa_bq, sa_bk, sa_bv, ta_bq, ta_bk, ta_bv,
                       qs, ks, vs, qt, kt, vt);

    hipLaunchKernelGGL(sattn_kernel, dim3(BB * TT), dim3(256), 0, stream,
                       qs, ks, vs, HS);

    hipLaunchKernelGGL(tattn_kernel, dim3(BB * NN), dim3(192), 0, stream,
                       qt, kt, vt, kpm, HT);

    hipLaunchKernelGGL(epi_kernel, dim3(PTOT / 64), dim3(256), 0, stream,
                       X, HS, HT, Wt8,
                       sa_bo1, sa_bo2, ta_bo1, ta_bo2, g_bxt, g_bh1, g_bh2,
                       out);
}

// Round 8
// 232.253 us; speedup vs baseline: 2.1969x; 1.0823x over previous
//
#include <hip/hip_runtime.h>
#include <math.h>

#define BB 16
#define TT 24
#define NN 128
#define DD 64
#define PTOT (BB * TT * NN)   // 49152 positions
#define P64  (PTOT * 64)      // elements per (B,T,N,64) buffer

typedef __attribute__((ext_vector_type(8))) short bf16x8;
typedef __attribute__((ext_vector_type(4))) float f32x4;

__device__ __forceinline__ unsigned short f2bf(float f) {
    unsigned u = __builtin_bit_cast(unsigned, f);
    u = (u + 0x7fffu + ((u >> 16) & 1u)) >> 16;   // round-to-nearest-even
    return (unsigned short)u;
}
__device__ __forceinline__ void unpack8(uint4 u, float* f) {
    f[0] = __builtin_bit_cast(float, u.x << 16);
    f[1] = __builtin_bit_cast(float, u.x & 0xFFFF0000u);
    f[2] = __builtin_bit_cast(float, u.y << 16);
    f[3] = __builtin_bit_cast(float, u.y & 0xFFFF0000u);
    f[4] = __builtin_bit_cast(float, u.z << 16);
    f[5] = __builtin_bit_cast(float, u.z & 0xFFFF0000u);
    f[6] = __builtin_bit_cast(float, u.w << 16);
    f[7] = __builtin_bit_cast(float, u.w & 0xFFFF0000u);
}
__device__ __forceinline__ uint4 pack8(const float* f) {
    uint4 o;
    o.x = (unsigned)f2bf(f[0]) | ((unsigned)f2bf(f[1]) << 16);
    o.y = (unsigned)f2bf(f[2]) | ((unsigned)f2bf(f[3]) << 16);
    o.z = (unsigned)f2bf(f[4]) | ((unsigned)f2bf(f[5]) << 16);
    o.w = (unsigned)f2bf(f[6]) | ((unsigned)f2bf(f[7]) << 16);
    return o;
}

// ---------------------------------------------------------------------------
// Kernel 0: combined weight prep.
// blocks 0..287: 6 proj weights (192x64) -> bf16 [j][n][k]  (Wt)
// blocks 288..415: 8 epi weights (64x64) -> bf16 [mat][n][k] (Wt8)
// ---------------------------------------------------------------------------
__global__ __launch_bounds__(256) void wprep_all(
    const float* __restrict__ W0, const float* __restrict__ W1,
    const float* __restrict__ W2, const float* __restrict__ W3,
    const float* __restrict__ W4, const float* __restrict__ W5,
    const float* __restrict__ E0, const float* __restrict__ E1,
    const float* __restrict__ E2, const float* __restrict__ E3,
    const float* __restrict__ E4, const float* __restrict__ E5,
    const float* __restrict__ E6, const float* __restrict__ E7,
    unsigned short* __restrict__ Wt, unsigned short* __restrict__ Wt8)
{
    const int bid = blockIdx.x;
    if (bid < 288) {
        const float* Ws[6] = {W0, W1, W2, W3, W4, W5};
        const int e = bid * 256 + threadIdx.x;          // < 73728
        const int j = e / 12288;
        const int r = e % 12288;
        const int k = r / 64;
        const int n = r % 64;
        Wt[j * 12288 + n * 192 + k] = f2bf(Ws[j][k * 64 + n]);
    } else {
        const float* Es[8] = {E0, E1, E2, E3, E4, E5, E6, E7};
        const int e = (bid - 288) * 256 + threadIdx.x;  // < 32768
        const int mat = e >> 12;
        const int r = e & 4095;
        const int k = r >> 6;
        const int n = r & 63;
        Wt8[mat * 4096 + n * 64 + k] = f2bf(Es[mat][k * 64 + n]);
    }
}

// ---------------------------------------------------------------------------
// Kernel 1: FUSED 6-way QKV projection + spatial attention.
// One block per (b,t): 128 positions, 256 threads (4 waves).
// GEMM phase: wave w owns channel tile nt=w; 36 weight frags cached in VGPRs;
// XE staged 16 rows at a time (double-buffered bf16 LDS); per mt: 36 MFMAs.
// Spatial q/k/v -> swizzled bf16 LDS (chunk XOR swizzle: conflict-free);
// temporal q/k/v -> global bf16.
// Attention phase: thread = (head, 4 query rows); single-pass softmax w/o max
// (inputs relu'd, dots bounded far below exp overflow).
// LDS: 2*16*200*2 + 3*128*64*2 = 61,952 B  (2 blocks/CU).
// ---------------------------------------------------------------------------
__global__ __launch_bounds__(256, 2) void fused_sattn(
    const float* __restrict__ X, const float* __restrict__ TLE,
    const unsigned short* __restrict__ Wt,   // [6][64][192] bf16
    const float* __restrict__ b0, const float* __restrict__ b1,
    const float* __restrict__ b2, const float* __restrict__ b3,
    const float* __restrict__ b4, const float* __restrict__ b5,
    unsigned short* __restrict__ qt, unsigned short* __restrict__ kt,
    unsigned short* __restrict__ vt,
    unsigned short* __restrict__ HS)
{
    __shared__ __align__(16) unsigned short xe[2][16][200];   // staged XE tile
    __shared__ __align__(16) unsigned short qq[128 * 64];     // swizzled bf16
    __shared__ __align__(16) unsigned short kk[128 * 64];
    __shared__ __align__(16) unsigned short vv[128 * 64];
    const int tid = threadIdx.x;
    const long p0 = (long)blockIdx.x * 128;
    const int w = tid >> 6, l = tid & 63, quad = l >> 4, l16 = l & 15;

    // ---- stage one 16-row XE tile (fp32 -> bf16) ----
    auto stage = [&](int mt, int buf) {
        #pragma unroll
        for (int i = 0; i < 3; ++i) {
            const int idx4 = tid + i * 256;     // < 768 (16 rows * 48 float4)
            const int m  = idx4 / 48;
            const int kq = idx4 % 48;
            const int k  = kq * 4;
            const long p = p0 + mt * 16 + m;
            float4 v;
            if (k < 64) v = *reinterpret_cast<const float4*>(X + p * 64 + k);
            else        v = *reinterpret_cast<const float4*>(TLE + p * 128 + (k - 64));
            ushort4 pk;
            pk.x = f2bf(v.x); pk.y = f2bf(v.y); pk.z = f2bf(v.z); pk.w = f2bf(v.w);
            *reinterpret_cast<ushort4*>(&xe[buf][m][k]) = pk;
        }
    };

    // ---- preload all 36 weight fragments (ch rows = w*16 + l16) ----
    bf16x8 wf[6][6];
    #pragma unroll
    for (int mat = 0; mat < 6; ++mat)
        #pragma unroll
        for (int kc = 0; kc < 6; ++kc)
            wf[mat][kc] = *reinterpret_cast<const bf16x8*>(
                &Wt[mat * 12288 + (w * 16 + l16) * 192 + kc * 32 + quad * 8]);

    const float* bias_p[6] = {b0, b1, b2, b3, b4, b5};
    float4 bias[6];
    #pragma unroll
    for (int mat = 0; mat < 6; ++mat)
        bias[mat] = *reinterpret_cast<const float4*>(&bias_p[mat][w * 16 + quad * 4]);

    stage(0, 0);
    __syncthreads();

    const int chunkW = ((w * 2 + (quad >> 1)));   // which 8-ch chunk this lane writes
    const int chSub  = (quad & 1) * 4;            // offset within chunk
    const int chBase = w * 16 + quad * 4;         // unswizzled channel base

    for (int mt = 0; mt < 8; ++mt) {
        if (mt < 7) stage(mt + 1, (mt + 1) & 1);

        bf16x8 A[6];
        #pragma unroll
        for (int kc = 0; kc < 6; ++kc)
            A[kc] = *reinterpret_cast<const bf16x8*>(
                &xe[mt & 1][l16][kc * 32 + quad * 8]);

        f32x4 acc[6];
        #pragma unroll
        for (int mat = 0; mat < 6; ++mat) acc[mat] = (f32x4){0.f, 0.f, 0.f, 0.f};
        #pragma unroll
        for (int kc = 0; kc < 6; ++kc)
            #pragma unroll
            for (int mat = 0; mat < 6; ++mat)
                acc[mat] = __builtin_amdgcn_mfma_f32_16x16x32_bf16(
                    wf[mat][kc], A[kc], acc[mat], 0, 0, 0);

        const int pos = mt * 16 + l16;            // lane's position (C/D col)
        const int sw  = pos * 64 + ((chunkW ^ (pos & 7)) << 3) + chSub;  // LDS addr
        unsigned short* dstS[3] = {qq, kk, vv};
        #pragma unroll
        for (int mat = 0; mat < 3; ++mat) {       // spatial -> LDS (relu'd)
            ushort4 pk;
            pk.x = f2bf(fmaxf(acc[mat][0] + bias[mat].x, 0.f));
            pk.y = f2bf(fmaxf(acc[mat][1] + bias[mat].y, 0.f));
            pk.z = f2bf(fmaxf(acc[mat][2] + bias[mat].z, 0.f));
            pk.w = f2bf(fmaxf(acc[mat][3] + bias[mat].w, 0.f));
            *reinterpret_cast<ushort4*>(&dstS[mat][sw]) = pk;
        }
        unsigned short* dstT[3] = {qt, kt, vt};
        const long gp = (p0 + pos) * 64 + chBase;
        #pragma unroll
        for (int m3 = 3; m3 < 6; ++m3) {          // temporal -> global bf16 (relu'd)
            ushort4 pk;
            pk.x = f2bf(fmaxf(acc[m3][0] + bias[m3].x, 0.f));
            pk.y = f2bf(fmaxf(acc[m3][1] + bias[m3].y, 0.f));
            pk.z = f2bf(fmaxf(acc[m3][2] + bias[m3].z, 0.f));
            pk.w = f2bf(fmaxf(acc[m3][3] + bias[m3].w, 0.f));
            *reinterpret_cast<ushort4*>(&dstT[m3 - 3][gp]) = pk;
        }
        __syncthreads();
    }

    // ---------------- attention phase ----------------
    const int h  = tid >> 5;          // head 0..7
    const int r0 = tid & 31;          // base query row
    const float scale = 0.35355339059327373f;  // 1/sqrt(8)

    float q[4][8];
    #pragma unroll
    for (int r = 0; r < 4; ++r) {
        const int row = r0 + r * 32;
        uint4 qu = *reinterpret_cast<const uint4*>(
            &qq[row * 64 + ((h ^ (row & 7)) << 3)]);
        float qf[8]; unpack8(qu, qf);
        #pragma unroll
        for (int d = 0; d < 8; ++d) q[r][d] = qf[d] * scale;
    }

    float sum[4] = {0.f, 0.f, 0.f, 0.f};
    float acc[4][8];
    #pragma unroll
    for (int r = 0; r < 4; ++r)
        #pragma unroll
        for (int d = 0; d < 8; ++d) acc[r][d] = 0.f;

    for (int m = 0; m < NN; ++m) {
        const int co = ((h ^ (m & 7)) << 3);
        uint4 ku = *reinterpret_cast<const uint4*>(&kk[m * 64 + co]);
        uint4 vu = *reinterpret_cast<const uint4*>(&vv[m * 64 + co]);
        float kf[8], vf[8];
        unpack8(ku, kf); unpack8(vu, vf);
        #pragma unroll
        for (int r = 0; r < 4; ++r) {
            float s = q[r][0] * kf[0];
            #pragma unroll
            for (int d = 1; d < 8; ++d) s = fmaf(q[r][d], kf[d], s);
            const float e = __expf(s);
            sum[r] += e;
            #pragma unroll
            for (int d = 0; d < 8; ++d) acc[r][d] = fmaf(e, vf[d], acc[r][d]);
        }
    }

    #pragma unroll
    for (int r = 0; r < 4; ++r) {
        const int row = r0 + r * 32;
        const float inv = 1.0f / sum[r];
        float o[8];
        #pragma unroll
        for (int d = 0; d < 8; ++d) o[d] = acc[r][d] * inv;
        *reinterpret_cast<uint4*>(&HS[(p0 + row) * 64 + h * 8]) = pack8(o);
    }
}

// ---------------------------------------------------------------------------
// Kernel 2: temporal attention (causal + key padding), bf16 I/O.
// One block per (b, n); 192 threads = (head h, query time i).
// ---------------------------------------------------------------------------
__global__ __launch_bounds__(192) void tattn_kernel(
    const unsigned short* __restrict__ Q, const unsigned short* __restrict__ Kb,
    const unsigned short* __restrict__ V, const int* __restrict__ kpm,
    unsigned short* __restrict__ O)
{
    __shared__ float kk[8][TT][8];
    __shared__ float vv[8][TT][8];
    const int tid = threadIdx.x;
    const int n = blockIdx.x & (NN - 1);
    const int b = blockIdx.x >> 7;

    {   // staging: thread = (head hs, time j): one 16-B bf16 load each for K and V
        const int hs = tid / TT;
        const int j  = tid % TT;
        const long g = (((long)(b * TT + j)) * NN + n) * 64 + hs * 8;
        uint4 ku = *reinterpret_cast<const uint4*>(&Kb[g]);
        uint4 vu = *reinterpret_cast<const uint4*>(&V[g]);
        float kf[8], vf[8];
        unpack8(ku, kf); unpack8(vu, vf);
        #pragma unroll
        for (int d = 0; d < 8; ++d) { kk[hs][j][d] = kf[d]; vv[hs][j][d] = vf[d]; }
    }

    const int h = tid / TT;
    const int i = tid % TT;
    const long qb = (((long)(b * TT + i)) * NN + n) * 64 + h * 8;
    float q[8];
    {
        uint4 qu = *reinterpret_cast<const uint4*>(&Q[qb]);
        unpack8(qu, q);
    }
    __syncthreads();

    const int kp = kpm[b];
    const float scale = 0.35355339059327373f;

    float s[TT];
    #pragma unroll
    for (int j = 0; j < TT; ++j) {
        float t = 0.0f;
        #pragma unroll
        for (int d = 0; d < 8; ++d) t = fmaf(q[d], kk[h][j][d], t);
        s[j] = (j <= i && j < kp) ? t * scale : -INFINITY;
    }
    float mx = -INFINITY;
    #pragma unroll
    for (int j = 0; j < TT; ++j) mx = fmaxf(mx, s[j]);

    float sum = 0.0f;
    float acc[8];
    #pragma unroll
    for (int d = 0; d < 8; ++d) acc[d] = 0.0f;
    #pragma unroll
    for (int j = 0; j < TT; ++j) {
        const float e = __expf(s[j] - mx);  // masked -> exp(-inf)=0
        sum += e;
        #pragma unroll
        for (int d = 0; d < 8; ++d) acc[d] = fmaf(e, vv[h][j][d], acc[d]);
    }
    const float inv = 1.0f / sum;
    float o[8];
    #pragma unroll
    for (int d = 0; d < 8; ++d) o[d] = acc[d] * inv;
    *reinterpret_cast<uint4*>(&O[qb]) = pack8(o);
}

// ---------------------------------------------------------------------------
// Kernel 3: epilogue via bf16 MFMA, swapped operands.
// Block = 256 thr (4 waves), 64-position tile.  Grid = PTOT/64 = 768.
// HS/HT arrive as bf16 -> staging is a straight copy (no conversion).
// ---------------------------------------------------------------------------
__global__ __launch_bounds__(256) void epi_kernel(
    const float* __restrict__ X,
    const unsigned short* __restrict__ HSb, const unsigned short* __restrict__ HTb,
    const unsigned short* __restrict__ Wt8,  // [8][64][64] bf16
    const float* __restrict__ sbo1, const float* __restrict__ sbo2,
    const float* __restrict__ tbo1, const float* __restrict__ tbo2,
    const float* __restrict__ bxt,
    const float* __restrict__ bh1, const float* __restrict__ bh2,
    float* __restrict__ out)
{
    constexpr int RS = 72;
    __shared__ __align__(16) unsigned short bufA[64][RS], bufB[64][RS], bufC[64][RS];
    const int tid = threadIdx.x;
    const long p0 = (long)blockIdx.x * 64;
    const int w = tid >> 6, l = tid & 63, quad = l >> 4, l16 = l & 15;
    const int chBase = w * 16 + quad * 4;

    // ---- stage HS -> bufA, HT -> bufC (straight bf16 copy) ----
    #pragma unroll
    for (int i = 0; i < 4; ++i) {
        const int idx = tid + i * 256;      // < 1024
        const int m = idx >> 4;
        const int c = (idx & 15) * 4;
        *reinterpret_cast<ushort4*>(&bufA[m][c]) =
            *reinterpret_cast<const ushort4*>(&HSb[(p0 + m) * 64 + c]);
        *reinterpret_cast<ushort4*>(&bufC[m][c]) =
            *reinterpret_cast<const ushort4*>(&HTb[(p0 + m) * 64 + c]);
    }
    __syncthreads();

    auto gemm = [&](const unsigned short (*in)[RS], int mat,
                    const float* __restrict__ bias, f32x4* accO) {
        bf16x8 af[2];
        #pragma unroll
        for (int kc = 0; kc < 2; ++kc)
            af[kc] = *reinterpret_cast<const bf16x8*>(
                &Wt8[mat * 4096 + (w * 16 + l16) * 64 + kc * 32 + quad * 8]);
        const float4 b4 = *reinterpret_cast<const float4*>(&bias[chBase]);
        #pragma unroll
        for (int pt = 0; pt < 4; ++pt) {
            f32x4 acc = (f32x4){0.f, 0.f, 0.f, 0.f};
            #pragma unroll
            for (int kc = 0; kc < 2; ++kc) {
                bf16x8 bf = *reinterpret_cast<const bf16x8*>(
                    &in[pt * 16 + l16][kc * 32 + quad * 8]);
                acc = __builtin_amdgcn_mfma_f32_16x16x32_bf16(af[kc], bf, acc, 0, 0, 0);
            }
            acc[0] += b4.x; acc[1] += b4.y; acc[2] += b4.z; acc[3] += b4.w;
            accO[pt] = acc;
        }
    };

    auto writeBuf = [&](unsigned short (*dst)[RS], const f32x4* v, bool relu) {
        #pragma unroll
        for (int pt = 0; pt < 4; ++pt) {
            float a0 = v[pt][0], a1 = v[pt][1], a2 = v[pt][2], a3 = v[pt][3];
            if (relu) { a0 = fmaxf(a0, 0.f); a1 = fmaxf(a1, 0.f);
                        a2 = fmaxf(a2, 0.f); a3 = fmaxf(a3, 0.f); }
            ushort4 pk; pk.x = f2bf(a0); pk.y = f2bf(a1); pk.z = f2bf(a2); pk.w = f2bf(a3);
            *reinterpret_cast<ushort4*>(&dst[pt * 16 + l16][chBase]) = pk;
        }
    };

    f32x4 t[4], HSr[4], HTr[4];

    gemm(bufA, 0, sbo1, t);                 // HS1 = relu(HS@sWo1+b)
    __syncthreads();
    writeBuf(bufB, t, true);
    __syncthreads();

    gemm(bufB, 1, sbo2, HSr);               // HS2 (fp32 regs)
    __syncthreads();
    writeBuf(bufA, HSr, false);
    __syncthreads();

    gemm(bufC, 2, tbo1, t);                 // HT1 = relu(HT@tWo1+b)
    __syncthreads();
    writeBuf(bufB, t, true);
    __syncthreads();

    gemm(bufB, 3, tbo2, HTr);               // HT2 (fp32 regs)
    __syncthreads();
    writeBuf(bufC, HTr, false);
    __syncthreads();

    // ---- gate ----
    {
        bf16x8 afS[2], afT[2];
        #pragma unroll
        for (int kc = 0; kc < 2; ++kc) {
            afS[kc] = *reinterpret_cast<const bf16x8*>(
                &Wt8[4 * 4096 + (w * 16 + l16) * 64 + kc * 32 + quad * 8]);
            afT[kc] = *reinterpret_cast<const bf16x8*>(
                &Wt8[5 * 4096 + (w * 16 + l16) * 64 + kc * 32 + quad * 8]);
        }
        const float4 b4 = *reinterpret_cast<const float4*>(&bxt[chBase]);
        #pragma unroll
        for (int pt = 0; pt < 4; ++pt) {
            f32x4 acc = (f32x4){0.f, 0.f, 0.f, 0.f};
            #pragma unroll
            for (int kc = 0; kc < 2; ++kc) {
                bf16x8 hsf = *reinterpret_cast<const bf16x8*>(
                    &bufA[pt * 16 + l16][kc * 32 + quad * 8]);
                acc = __builtin_amdgcn_mfma_f32_16x16x32_bf16(afS[kc], hsf, acc, 0, 0, 0);
            }
            #pragma unroll
            for (int kc = 0; kc < 2; ++kc) {
                bf16x8 htf = *reinterpret_cast<const bf16x8*>(
                    &bufC[pt * 16 + l16][kc * 32 + quad * 8]);
                acc = __builtin_amdgcn_mfma_f32_16x16x32_bf16(afT[kc], htf, acc, 0, 0, 0);
            }
            const float zb[4] = {acc[0] + b4.x, acc[1] + b4.y, acc[2] + b4.z, acc[3] + b4.w};
            f32x4 h;
            #pragma unroll
            for (int r = 0; r < 4; ++r) {
                const float z = 1.0f / (1.0f + __expf(-zb[r]));
                h[r] = z * HSr[pt][r] + (1.0f - z) * HTr[pt][r];
            }
            t[pt] = h;
        }
    }
    __syncthreads();
    writeBuf(bufB, t, false);
    __syncthreads();

    gemm(bufB, 6, bh1, t);                  // H1 = relu(H@Wh1+b)
    __syncthreads();
    writeBuf(bufA, t, true);
    __syncthreads();

    gemm(bufA, 7, bh2, t);                  // out = X + H1@Wh2+b
    #pragma unroll
    for (int pt = 0; pt < 4; ++pt) {
        const long pos = p0 + pt * 16 + l16;
        const float4 xv = *reinterpret_cast<const float4*>(&X[pos * 64 + chBase]);
        float4 o;
        o.x = t[pt][0] + xv.x; o.y = t[pt][1] + xv.y;
        o.z = t[pt][2] + xv.z; o.w = t[pt][3] + xv.w;
        *reinterpret_cast<float4*>(&out[pos * 64 + chBase]) = o;
    }
}

// ---------------------------------------------------------------------------
extern "C" void kernel_launch(void* const* d_in, const int* in_sizes, int n_in,
                              void* d_out, int out_size, void* d_ws, size_t ws_size,
                              hipStream_t stream) {
    const float* X   = (const float*)d_in[0];
    const float* TLE = (const float*)d_in[1];
    const int* kpm   = (const int*)d_in[2];

    const float* sa_Wq = (const float*)d_in[3];  const float* sa_bq = (const float*)d_in[4];
    const float* sa_Wk = (const float*)d_in[5];  const float* sa_bk = (const float*)d_in[6];
    const float* sa_Wv = (const float*)d_in[7];  const float* sa_bv = (const float*)d_in[8];
    const float* sa_Wo1 = (const float*)d_in[9];  const float* sa_bo1 = (const float*)d_in[10];
    const float* sa_Wo2 = (const float*)d_in[11]; const float* sa_bo2 = (const float*)d_in[12];
    const float* ta_Wq = (const float*)d_in[13]; const float* ta_bq = (const float*)d_in[14];
    const float* ta_Wk = (const float*)d_in[15]; const float* ta_bk = (const float*)d_in[16];
    const float* ta_Wv = (const float*)d_in[17]; const float* ta_bv = (const float*)d_in[18];
    const float* ta_Wo1 = (const float*)d_in[19]; const float* ta_bo1 = (const float*)d_in[20];
    const float* ta_Wo2 = (const float*)d_in[21]; const float* ta_bo2 = (const float*)d_in[22];
    const float* g_Wxs = (const float*)d_in[23];
    const float* g_Wxt = (const float*)d_in[24]; const float* g_bxt = (const float*)d_in[25];
    const float* g_Wh1 = (const float*)d_in[26]; const float* g_bh1 = (const float*)d_in[27];
    const float* g_Wh2 = (const float*)d_in[28]; const float* g_bh2 = (const float*)d_in[29];

    unsigned short* wsp = (unsigned short*)d_ws;
    unsigned short* qt  = wsp + 0L * P64;
    unsigned short* kt  = wsp + 1L * P64;
    unsigned short* vt  = wsp + 2L * P64;
    unsigned short* HSb = wsp + 3L * P64;
    unsigned short* HTb = wsp + 4L * P64;
    unsigned short* Wt  = wsp + 5L * P64;            // 6*64*192 bf16
    unsigned short* Wt8 = Wt + 6 * 12288;            // 8*64*64 bf16

    float* out = (float*)d_out;

    hipLaunchKernelGGL(wprep_all, dim3(416), dim3(256), 0, stream,
                       sa_Wq, sa_Wk, sa_Wv, ta_Wq, ta_Wk, ta_Wv,
                       sa_Wo1, sa_Wo2, ta_Wo1, ta_Wo2, g_Wxs, g_Wxt, g_Wh1, g_Wh2,
                       Wt, Wt8);

    hipLaunchKernelGGL(fused_sattn, dim3(BB * TT), dim3(256), 0, stream,
                       X, TLE, Wt,
                       sa_bq, sa_bk, sa_bv, ta_bq, ta_bk, ta_bv,
                       qt, kt, vt, HSb);

    hipLaunchKernelGGL(tattn_kernel, dim3(BB * NN), dim3(192), 0, stream,
                       qt, kt, vt, kpm, HTb);

    hipLaunchKernelGGL(epi_kernel, dim3(PTOT / 64), dim3(256), 0, stream,
                       X, HSb, HTb, Wt8,
                       sa_bo1, sa_bo2, ta_bo1, ta_bo2, g_bxt, g_bh1, g_bh2,
                       out);
}